// Round 3
// baseline (292.364 us; speedup 1.0000x reference)
//
#include <hip/hip_runtime.h>

#define S_LEN 8192
#define C_CTX 21
#define E_DIM 128
#define G_DIM 36
#define H_DIM 1024
#define T_TAG 32
#define D_RAW 3444          // 21*(128+36)
#define DP 3456             // padded to multiple of 64 (54 K-tiles of 64)
#define START_TAG 30
#define STOP_TAG 31
#define NEGV -10000.0f
#define K_CHUNKS 64
#define L_CHUNK 128         // K_CHUNKS * L_CHUNK == S_LEN

typedef __bf16 bf16_t;
typedef __bf16 bf16x4 __attribute__((ext_vector_type(4)));
typedef __bf16 bf16x8 __attribute__((ext_vector_type(8)));
typedef float  f32x4  __attribute__((ext_vector_type(4)));
typedef float  f32x16 __attribute__((ext_vector_type(16)));

__device__ inline void async_copy16(const bf16_t* g, bf16_t* l) {
    __builtin_amdgcn_global_load_lds(
        (const __attribute__((address_space(1))) void*)g,
        (__attribute__((address_space(3))) void*)l, 16, 0, 0);
}

// ---------------- Phase 0: materialize padded bf16 X and W1 ----------------
// 4 cols per thread: 164 = 41 groups of 4; groups never straddle emb/gz.
__global__ void build_x(const int* __restrict__ ctx, const float* __restrict__ gz,
                        const float* __restrict__ emb, bf16_t* __restrict__ X) {
    const int s = blockIdx.x;
    for (int g = threadIdx.x; g < DP / 4; g += 256) {   // 864 groups
        float4 v = {0.f, 0.f, 0.f, 0.f};
        if (g < D_RAW / 4) {                             // 861 real groups
            const int c  = g / 41;
            const int rg = g - c * 41;                   // 0..40
            if (rg < 32) v = *(const float4*)&emb[(size_t)ctx[s * C_CTX + c] * E_DIM + rg * 4];
            else         v = *(const float4*)&gz[((size_t)s * C_CTX + c) * G_DIM + (rg - 32) * 4];
        }
        bf16x4 o = {(bf16_t)v.x, (bf16_t)v.y, (bf16_t)v.z, (bf16_t)v.w};
        *(bf16x4*)&X[(size_t)s * DP + g * 4] = o;
    }
}

__global__ void build_w1b(const float* __restrict__ w1, bf16_t* __restrict__ W) {
    const int h = blockIdx.x;
    for (int g = threadIdx.x; g < DP / 4; g += 256) {
        float4 v = {0.f, 0.f, 0.f, 0.f};
        if (g < D_RAW / 4) v = *(const float4*)&w1[(size_t)h * D_RAW + g * 4];
        bf16x4 o = {(bf16_t)v.x, (bf16_t)v.y, (bf16_t)v.z, (bf16_t)v.w};
        *(bf16x4*)&W[(size_t)h * DP + g * 4] = o;
    }
}

// ---------------- Phase 1: h = relu(X @ W1^T + b1), bf16 MFMA -------------
// 256x128 tile, BK=64, 512 threads (8 waves, 4M x 2N, 64x64 per wave).
// v_mfma_f32_32x32x16_bf16: 2x2 fragments of 32x32 per wave. Per K-tile per
// wave: 16 ds_read_b128 feed 16 MFMA (32 FLOP/LDS-byte vs 21.8 for the
// 16x16x32 variant) — the binding resource was LDS read BW + barrier count,
// so the bigger MFMA shape raises the MFMA:(LDS+barrier) cycle ratio.
// One phase per K-tile: {16 ds_read + 6 global_load_lds -> s_barrier ->
// setprio(1) -> 16 MFMA -> setprio(0) -> counted vmcnt (never 0 mid-loop) ->
// s_barrier}. Triple-buffered K-tiles, prefetch distance 2: tile-end
// vmcnt(6) leaves next-next tile's 6 loads in flight across the barrier.
// LDS k-group swizzle kg ^ (row&7): inverse-swizzled global source + linear
// global_load_lds dest + swizzled ds_read (both-sides-or-neither).
__global__ __launch_bounds__(512) void gemm1(const bf16_t* __restrict__ X,
                                             const bf16_t* __restrict__ W,
                                             const float* __restrict__ b1,
                                             bf16_t* __restrict__ Hout) {
    __shared__ bf16_t As[3][256 * 64];   // 3 x 32 KB
    __shared__ bf16_t Bs[3][128 * 64];   // 3 x 16 KB  (total 144 KB, 1 block/CU)
    const int tid  = threadIdx.x;
    const int wave = tid >> 6, lane = tid & 63;
    const int s0 = blockIdx.x * 256, h0 = blockIdx.y * 128;
    const int wm = (wave >> 1) * 64;     // 4 wave-rows
    const int wn = (wave & 1) * 64;      // 2 wave-cols

    // staging: load l = i*512+tid -> LDS row l/8 = i*64 + (tid>>3), group tid&7
    // source k-group inverse-swizzled so that LDS[row][g] = X[row][(g^(row&7))*8..]
    const int arow = tid >> 3;                         // 0..63
    const int akg  = (tid & 7) ^ (arow & 7);
    const bf16_t* gA = X + (size_t)(s0 + arow) * DP + akg * 8;
    const bf16_t* gB = W + (size_t)(h0 + arow) * DP + akg * 8;

    // 32x32x16 operand mapping: lane l holds row (l&31), k = (l>>5)*8 + 0..7
    const int r32 = lane & 31;
    const int kh  = lane >> 5;           // 0/1: k-half within a K=16 slice
    const int r7  = r32 & 7;

#define STAGE_A(buf, k0, i) async_copy16(gA + (size_t)(i) * 64 * DP + (k0), &As[buf][((i) * 512 + tid) * 8])
#define STAGE_B(buf, k0, i) async_copy16(gB + (size_t)(i) * 64 * DP + (k0), &Bs[buf][((i) * 512 + tid) * 8])

    // prologue: tiles 0 and 1 (12 loads in flight)
    STAGE_A(0, 0, 0); STAGE_A(0, 0, 1); STAGE_A(0, 0, 2); STAGE_A(0, 0, 3);
    STAGE_B(0, 0, 0); STAGE_B(0, 0, 1);
    STAGE_A(1, 64, 0); STAGE_A(1, 64, 1); STAGE_A(1, 64, 2); STAGE_A(1, 64, 3);
    STAGE_B(1, 64, 0); STAGE_B(1, 64, 1);
    asm volatile("s_waitcnt vmcnt(6)" ::: "memory");   // tile 0 landed; tile 1 in flight
    __builtin_amdgcn_s_barrier();

    f32x16 acc[2][2] = {};
    const int NT = DP / 64;              // 54
    int rb = 0;
    for (int t = 0; t < NT; ++t) {
        const int  sb = (rb == 0) ? 2 : rb - 1;   // (t+2)%3: buffer of tile t-1, reads done
        const int  k2 = (t + 2) * 64;
        const bool st = (t + 2) < NT;

        // all 16 register fragments for this K-tile (16 x ds_read_b128)
        bf16x8 a[4][2], b[4][2];     // [ks][frag]
#pragma unroll
        for (int ks = 0; ks < 4; ++ks) {
            const int slot = ((ks * 2 + kh) ^ r7) * 8;   // swizzled 16B k-group
#pragma unroll
            for (int mt = 0; mt < 2; ++mt)
                a[ks][mt] = *(const bf16x8*)&As[rb][(wm + mt * 32 + r32) * 64 + slot];
#pragma unroll
            for (int nt = 0; nt < 2; ++nt)
                b[ks][nt] = *(const bf16x8*)&Bs[rb][(wn + nt * 32 + r32) * 64 + slot];
        }
        // stage next-next tile's 6 loads (issue-early; land under MFMA)
        if (st) {
            STAGE_A(sb, k2, 0); STAGE_A(sb, k2, 1); STAGE_A(sb, k2, 2); STAGE_A(sb, k2, 3);
            STAGE_B(sb, k2, 0); STAGE_B(sb, k2, 1);
        }
        __builtin_amdgcn_s_barrier();         // reads + loads in flight while waiting
        __builtin_amdgcn_s_setprio(1);
#pragma unroll
        for (int ks = 0; ks < 4; ++ks)        // ks outer: 4 independent MFMA per chain step
#pragma unroll
            for (int mt = 0; mt < 2; ++mt)
#pragma unroll
                for (int nt = 0; nt < 2; ++nt)
                    acc[mt][nt] = __builtin_amdgcn_mfma_f32_32x32x16_bf16(
                        a[ks][mt], b[ks][nt], acc[mt][nt], 0, 0, 0);
        __builtin_amdgcn_s_setprio(0);
        // tile-boundary wait: next tile's 6 loads (oldest outstanding) landed;
        // newest 6 (tile t+2) stay in flight across the barrier.
        if (st)              asm volatile("s_waitcnt vmcnt(6)" ::: "memory");
        else if (t + 1 < NT) asm volatile("s_waitcnt vmcnt(0)" ::: "memory");
        __builtin_amdgcn_s_barrier();
        rb = (rb == 2) ? 0 : rb + 1;
    }
#undef STAGE_A
#undef STAGE_B

    // C/D layout for 32x32: col = lane&31, row = (reg&3) + 8*(reg>>2) + 4*(lane>>5)
    const int ccol = lane & 31;
#pragma unroll
    for (int nt = 0; nt < 2; ++nt) {
        const int j = h0 + wn + nt * 32 + ccol;
        const float bv = b1[j];
#pragma unroll
        for (int mt = 0; mt < 2; ++mt) {
#pragma unroll
            for (int i = 0; i < 16; ++i) {
                const int row = (i & 3) + 8 * (i >> 2) + 4 * kh;
                const int s = s0 + wm + mt * 32 + row;
                const float v = acc[mt][nt][i] + bv;
                Hout[(size_t)s * H_DIM + j] = (bf16_t)fmaxf(v, 0.f);
            }
        }
    }
}

// ---------------- Phase 2: feats = H @ w2^T + b2 (fp32 out), MFMA ----------
// M=128 x N=32, BK=64 (16 iters). A via global_load_lds; B converted fp32->bf16
// in-kernel. 64-wide rows: swizzle kg ^ (row&7).
__global__ __launch_bounds__(256) void feats_mfma(const bf16_t* __restrict__ Hb,
                                                  const float* __restrict__ w2,
                                                  const float* __restrict__ b2,
                                                  float* __restrict__ F) {
    __shared__ bf16_t As[128 * 64];
    __shared__ bf16_t Bs[32 * 64];
    const int tid  = threadIdx.x;
    const int wave = tid >> 6, lane = tid & 63;
    const int s0 = blockIdx.x * 128;
    const int wm = wave * 32;

    // A staging: chunk i*256+tid -> row = i*32 + (tid>>3), kg = tid&7
    const int arow = tid >> 3;
    const int akgs = (tid & 7) ^ (arow & 7);          // (i*32+arow)&7 == arow&7
    const bf16_t* gA = Hb + (size_t)(s0 + arow) * H_DIM + akgs * 8;
    // B staging: row = tid>>3 (0..31), kg = tid&7
    const int brow = tid >> 3;
    const int bkgs = (tid & 7) ^ (brow & 7);
    const float* wp = w2 + (size_t)brow * H_DIM + bkgs * 8;
    bf16_t* lB = &Bs[tid * 8];

    const int lrow = lane & 15;

    f32x4 acc[2][2] = {};
    for (int k0 = 0; k0 < H_DIM; k0 += 64) {
#pragma unroll
        for (int i = 0; i < 4; ++i)
            async_copy16(gA + (size_t)i * 32 * H_DIM + k0, &As[(tid + i * 256) * 8]);
        const float4 x0 = *(const float4*)(wp + k0);
        const float4 x1 = *(const float4*)(wp + k0 + 4);
        bf16x8 bb = {(bf16_t)x0.x, (bf16_t)x0.y, (bf16_t)x0.z, (bf16_t)x0.w,
                     (bf16_t)x1.x, (bf16_t)x1.y, (bf16_t)x1.z, (bf16_t)x1.w};
        *(bf16x8*)lB = bb;
        __syncthreads();
#pragma unroll
        for (int ks = 0; ks < 2; ++ks) {
            const int kq = ((ks * 4 + (lane >> 4)) ^ (lrow & 7)) * 8;
            bf16x8 a[2], b[2];
#pragma unroll
            for (int mt = 0; mt < 2; ++mt)
                a[mt] = *(const bf16x8*)&As[(wm + mt * 16 + lrow) * 64 + kq];
#pragma unroll
            for (int nt = 0; nt < 2; ++nt)
                b[nt] = *(const bf16x8*)&Bs[(nt * 16 + lrow) * 64 + kq];
#pragma unroll
            for (int mt = 0; mt < 2; ++mt)
#pragma unroll
                for (int nt = 0; nt < 2; ++nt)
                    acc[mt][nt] = __builtin_amdgcn_mfma_f32_16x16x32_bf16(a[mt], b[nt], acc[mt][nt], 0, 0, 0);
        }
        __syncthreads();
    }
    const int crow = (lane >> 4) * 4;
    const int ccol = lane & 15;
#pragma unroll
    for (int nt = 0; nt < 2; ++nt) {
        const int j = nt * 16 + ccol;
        const float bv = b2[j];
#pragma unroll
        for (int mt = 0; mt < 2; ++mt) {
#pragma unroll
            for (int r = 0; r < 4; ++r) {
                const int s = s0 + wm + mt * 16 + crow + r;
                F[(size_t)s * T_TAG + j] = acc[mt][nt][r] + bv;
            }
        }
    }
}

// ---------------- CRF pass A: per-chunk matrix-chain products --------------
// v round-trips through a per-wave LDS slice (wave-lockstep => barrier-free):
// 1 ds_write + 8 broadcast ds_read_b128 per step instead of 32 bpermutes.
__global__ __launch_bounds__(256) void crfA(const float* __restrict__ F,
                                            const float* __restrict__ trans,
                                            float* __restrict__ QT,
                                            float* __restrict__ sigma) {
    __shared__ float fl[L_CHUNK * 32];
    __shared__ float vb[4][2][32];
    const int c    = blockIdx.x >> 2;
    const int tid  = threadIdx.x;
    const int wave = tid >> 6;
    const int lane = tid & 63;
    const int n    = lane & 31;
    const int pl   = lane >> 5;
    const int p    = ((blockIdx.x & 3) << 3) + (wave << 1) + pl;
    const int s0   = c * L_CHUNK;
    for (int i = tid; i < L_CHUNK * 32; i += 256) fl[i] = F[(size_t)s0 * 32 + i];
    __syncthreads();

    float et[32];
#pragma unroll
    for (int k = 0; k < 32; ++k) et[k] = __expf(trans[n * 32 + k]);

    float* vrow = &vb[wave][pl][0];
    float v  = __expf(trans[n * 32 + p] + fl[n]);
    float sg = 0.f;
    for (int s = 1; s < L_CHUNK; ++s) {
        vrow[n] = v;
        __builtin_amdgcn_s_waitcnt(0xC07F);   // lgkmcnt(0): wave-coherent LDS
        float a0 = 0.f, a1 = 0.f, a2 = 0.f, a3 = 0.f;
#pragma unroll
        for (int q = 0; q < 8; ++q) {
            const float4 wv = *(const float4*)&vrow[q * 4];
            a0 = __builtin_fmaf(et[q * 4 + 0], wv.x, a0);
            a1 = __builtin_fmaf(et[q * 4 + 1], wv.y, a1);
            a2 = __builtin_fmaf(et[q * 4 + 2], wv.z, a2);
            a3 = __builtin_fmaf(et[q * 4 + 3], wv.w, a3);
        }
        v = __expf(fl[s * 32 + n]) * ((a0 + a1) + (a2 + a3));
        if ((s & 7) == 7) {
            float m = v;
#pragma unroll
            for (int off = 16; off; off >>= 1) m = fmaxf(m, __shfl_xor(m, off, 32));
            if (m > 0.f) { v *= 1.0f / m; sg += __logf(m); }
        }
    }
    QT[(c * 32 + p) * 32 + n] = v;
    if (n == 0) sigma[c * 32 + p] = sg;
}

// ---------------- CRF pass B: parallel matrix fold ----------------
__global__ __launch_bounds__(1024) void crf_fold(const float* __restrict__ Qin,
                                                 const float* __restrict__ Sin,
                                                 const int fold, const int final,
                                                 float* __restrict__ Qout,
                                                 float* __restrict__ Sout,
                                                 const float* __restrict__ trans,
                                                 const float* __restrict__ F,
                                                 const int* __restrict__ lab,
                                                 float* __restrict__ out) {
    __shared__ float A[32][33];
    __shared__ float M[32][33];
    __shared__ float sgf[32];
    __shared__ float gred[16];
    __shared__ float gold_s;

    const int t = threadIdx.x;
    const int p = t >> 5, n = t & 31;
    const int c0 = blockIdx.x * fold;

    if (final) {
        float ga = 0.f;
        for (int s = t; s < S_LEN; s += 1024) {
            const int tg = lab[s];
            ga += F[(size_t)s * T_TAG + tg];
            const int tp = (s == 0) ? START_TAG : lab[s - 1];
            ga += trans[tg * T_TAG + tp];
        }
        if (t == 0) ga += trans[STOP_TAG * T_TAG + lab[S_LEN - 1]];
#pragma unroll
        for (int off = 32; off; off >>= 1) ga += __shfl_down(ga, off, 64);
        if ((t & 63) == 0) gred[t >> 6] = ga;
    }

    A[n][p] = Qin[(size_t)(c0 * 32 + p) * 32 + n];
    float sA = Sin[c0 * 32 + p];
    float mreg = Qin[(size_t)((c0 + 1) * 32 + p) * 32 + n];

    for (int i = 1; i < fold; ++i) {
        const float sMn = Sin[(c0 + i) * 32 + n];
        float mmax = sMn;
#pragma unroll
        for (int off = 16; off; off >>= 1) mmax = fmaxf(mmax, __shfl_xor(mmax, off, 32));
        const float sMp = Sin[(c0 + i) * 32 + p];
        __syncthreads();
        M[n][p] = mreg * __expf(sMp - mmax);
        if (i + 1 < fold) mreg = Qin[(size_t)((c0 + i + 1) * 32 + p) * 32 + n];
        __syncthreads();
        float acc = 0.f;
#pragma unroll 8
        for (int k = 0; k < 32; ++k)
            acc += M[n][k] * A[k][p];
        float cm = acc;
#pragma unroll
        for (int off = 16; off; off >>= 1) cm = fmaxf(cm, __shfl_xor(cm, off, 32));
        cm = fmaxf(cm, 1e-37f);
        __syncthreads();
        A[n][p] = acc / cm;
        sA = sA + mmax + __logf(cm);
    }
    __syncthreads();

    if (!final) {
        Qout[(size_t)(blockIdx.x * 32 + p) * 32 + n] = A[n][p];
        if (n == 0) Sout[blockIdx.x * 32 + p] = sA;
        return;
    }

    if (n == 0) sgf[p] = sA;
    if (t == 0) {
        float s = 0.f;
#pragma unroll
        for (int i = 0; i < 16; ++i) s += gred[i];
        gold_s = s;
    }
    __syncthreads();
    if (t < 32) {
        float v = A[t][START_TAG] * __expf(trans[STOP_TAG * T_TAG + t]);
#pragma unroll
        for (int off = 16; off; off >>= 1) v += __shfl_xor(v, off, 32);
        if (t == 0) out[0] = sgf[START_TAG] + __logf(v) - gold_s;
    }
}

// ---------------- launch ----------------
extern "C" void kernel_launch(void* const* d_in, const int* in_sizes, int n_in,
                              void* d_out, int out_size, void* d_ws, size_t ws_size,
                              hipStream_t stream) {
    const int*   ctx   = (const int*)d_in[0];
    const float* gz    = (const float*)d_in[1];
    const int*   lab   = (const int*)d_in[2];
    const float* emb   = (const float*)d_in[3];
    const float* w1    = (const float*)d_in[4];
    const float* b1    = (const float*)d_in[5];
    const float* w2    = (const float*)d_in[6];
    const float* b2    = (const float*)d_in[7];
    const float* trans = (const float*)d_in[8];
    float* out = (float*)d_out;

    char* ws = (char*)d_ws;
    bf16_t* Xb  = (bf16_t*)(ws + 0);               // 8192*3456*2 = 56,623,104
    bf16_t* W1b = (bf16_t*)(ws + 56623104);        // 1024*3456*2 =  7,077,888
    bf16_t* Hb  = (bf16_t*)(ws + 63700992);        // 8192*1024*2 = 16,777,216
    float*  F   = (float*)(ws + 80478208);         // 8192*32*4   =  1,048,576
    float*  QT  = (float*)(ws + 81526784);         // 64*32*32*4  =    262,144
    float*  sg  = (float*)(ws + 81788928);         // 64*32*4     =      8,192
    // fold temporaries overlay the Xb region (consumed after gemm1):
    float*  Q1  = (float*)(ws + 65536);            // 16*32*32*4  =     65,536
    float*  S1  = (float*)(ws + 131072);           // 16*32*4     =      2,048

    build_x<<<S_LEN, 256, 0, stream>>>(ctx, gz, emb, Xb);
    build_w1b<<<H_DIM, 256, 0, stream>>>(w1, W1b);
    gemm1<<<dim3(S_LEN / 256, H_DIM / 128), 512, 0, stream>>>(Xb, W1b, b1, Hb);
    feats_mfma<<<S_LEN / 128, 256, 0, stream>>>(Hb, w2, b2, F);
    crfA<<<K_CHUNKS * 4, 256, 0, stream>>>(F, trans, QT, sg);
    crf_fold<<<16, 1024, 0, stream>>>(QT, sg, 4, 0, Q1, S1, trans, F, lab, out);
    crf_fold<<<1, 1024, 0, stream>>>(Q1, S1, 16, 1, nullptr, nullptr, trans, F, lab, out);
}

// Round 4
// 279.236 us; speedup vs baseline: 1.0470x; 1.0470x over previous
//
#include <hip/hip_runtime.h>

#define S_LEN 8192
#define C_CTX 21
#define E_DIM 128
#define G_DIM 36
#define H_DIM 1024
#define T_TAG 32
#define D_RAW 3444          // 21*(128+36)
#define DP 3456             // padded to multiple of 64 (54 K-tiles of 64)
#define START_TAG 30
#define STOP_TAG 31
#define NEGV -10000.0f
#define K_CHUNKS 64
#define L_CHUNK 128         // K_CHUNKS * L_CHUNK == S_LEN

typedef __bf16 bf16_t;
typedef __bf16 bf16x4 __attribute__((ext_vector_type(4)));
typedef __bf16 bf16x8 __attribute__((ext_vector_type(8)));
typedef float  f32x4  __attribute__((ext_vector_type(4)));

__device__ inline void async_copy16(const bf16_t* g, bf16_t* l) {
    __builtin_amdgcn_global_load_lds(
        (const __attribute__((address_space(1))) void*)g,
        (__attribute__((address_space(3))) void*)l, 16, 0, 0);
}

// ---------------- Phase 0: materialize padded bf16 X and W1 ----------------
// 4 cols per thread: 164 = 41 groups of 4; groups never straddle emb/gz.
__global__ void build_x(const int* __restrict__ ctx, const float* __restrict__ gz,
                        const float* __restrict__ emb, bf16_t* __restrict__ X) {
    const int s = blockIdx.x;
    for (int g = threadIdx.x; g < DP / 4; g += 256) {   // 864 groups
        float4 v = {0.f, 0.f, 0.f, 0.f};
        if (g < D_RAW / 4) {                             // 861 real groups
            const int c  = g / 41;
            const int rg = g - c * 41;                   // 0..40
            if (rg < 32) v = *(const float4*)&emb[(size_t)ctx[s * C_CTX + c] * E_DIM + rg * 4];
            else         v = *(const float4*)&gz[((size_t)s * C_CTX + c) * G_DIM + (rg - 32) * 4];
        }
        bf16x4 o = {(bf16_t)v.x, (bf16_t)v.y, (bf16_t)v.z, (bf16_t)v.w};
        *(bf16x4*)&X[(size_t)s * DP + g * 4] = o;
    }
}

__global__ void build_w1b(const float* __restrict__ w1, bf16_t* __restrict__ W) {
    const int h = blockIdx.x;
    for (int g = threadIdx.x; g < DP / 4; g += 256) {
        float4 v = {0.f, 0.f, 0.f, 0.f};
        if (g < D_RAW / 4) v = *(const float4*)&w1[(size_t)h * D_RAW + g * 4];
        bf16x4 o = {(bf16_t)v.x, (bf16_t)v.y, (bf16_t)v.z, (bf16_t)v.w};
        *(bf16x4*)&W[(size_t)h * DP + g * 4] = o;
    }
}

// ---------------- Phase 1: h = relu(X @ W1^T + b1), bf16 MFMA -------------
// 256x128 tile, BK=64, 512 threads (8 waves, 4M x 2N, 64x64 per wave).
// 16x16x32 MFMA (conflict-free read pattern: 16 distinct rows per b128,
// lane>>4 picks the k-slot — verified 0 bank conflicts; the 32x32 shape is
// structurally >=4-way conflicted at 128B LDS rows and was reverted).
// Single phase per K-tile (2 barriers, not 4) and B fragments read ONCE
// (16 ds_read_b128/wave/tile, not 24): {16 ds_read + 6 global_load_lds ->
// s_barrier -> setprio(1) -> 32 MFMA -> setprio(0) -> counted vmcnt (never 0
// mid-loop) -> s_barrier}. Triple-buffered K-tiles, prefetch distance 2:
// tile-end vmcnt(6) leaves next-next tile's 6 loads in flight across the
// barrier. LDS k-group swizzle kg ^ (row&7): inverse-swizzled global source
// + linear global_load_lds dest + swizzled ds_read (both-sides-or-neither).
__global__ __launch_bounds__(512) void gemm1(const bf16_t* __restrict__ X,
                                             const bf16_t* __restrict__ W,
                                             const float* __restrict__ b1,
                                             bf16_t* __restrict__ Hout) {
    __shared__ bf16_t As[3][256 * 64];   // 3 x 32 KB
    __shared__ bf16_t Bs[3][128 * 64];   // 3 x 16 KB  (total 144 KB, 1 block/CU)
    const int tid  = threadIdx.x;
    const int wave = tid >> 6, lane = tid & 63;
    const int s0 = blockIdx.x * 256, h0 = blockIdx.y * 128;
    const int wm = (wave >> 1) * 64;     // 4 wave-rows
    const int wn = (wave & 1) * 64;      // 2 wave-cols

    // staging: load l = i*512+tid -> LDS row l/8 = i*64 + (tid>>3), group tid&7
    // source k-group inverse-swizzled so that LDS[row][g] = X[row][(g^(row&7))*8..]
    const int arow = tid >> 3;                         // 0..63
    const int akg  = (tid & 7) ^ (arow & 7);
    const bf16_t* gA = X + (size_t)(s0 + arow) * DP + akg * 8;
    const bf16_t* gB = W + (size_t)(h0 + arow) * DP + akg * 8;

    const int lrow  = lane & 15;
    const int khalf = lane >> 4;         // 0..3
    const int lr7   = lrow & 7;

#define STAGE_A(buf, k0, i) async_copy16(gA + (size_t)(i) * 64 * DP + (k0), &As[buf][((i) * 512 + tid) * 8])
#define STAGE_B(buf, k0, i) async_copy16(gB + (size_t)(i) * 64 * DP + (k0), &Bs[buf][((i) * 512 + tid) * 8])

    // prologue: tiles 0 and 1 (12 loads in flight)
    STAGE_A(0, 0, 0); STAGE_A(0, 0, 1); STAGE_A(0, 0, 2); STAGE_A(0, 0, 3);
    STAGE_B(0, 0, 0); STAGE_B(0, 0, 1);
    STAGE_A(1, 64, 0); STAGE_A(1, 64, 1); STAGE_A(1, 64, 2); STAGE_A(1, 64, 3);
    STAGE_B(1, 64, 0); STAGE_B(1, 64, 1);
    asm volatile("s_waitcnt vmcnt(6)" ::: "memory");   // tile 0 landed; tile 1 in flight
    __builtin_amdgcn_s_barrier();

    f32x4 acc[4][4] = {};
    const int NT = DP / 64;              // 54
    int rb = 0;
    for (int t = 0; t < NT; ++t) {
        const int  sb = (rb == 0) ? 2 : rb - 1;   // (t+2)%3: buffer of tile t-1, reads done
        const int  k2 = (t + 2) * 64;
        const bool st = (t + 2) < NT;

        // all register fragments for this K-tile: 8 A + 8 B = 16 ds_read_b128
        bf16x8 a[2][2][2];     // [sp][ks][mt]
        bf16x8 b[2][2][2];     // [qn][ks][nt]
#pragma unroll
        for (int ks = 0; ks < 2; ++ks) {
            const int kgr = ((ks * 4 + khalf) ^ lr7) * 8;
#pragma unroll
            for (int sp = 0; sp < 2; ++sp)
#pragma unroll
                for (int mt = 0; mt < 2; ++mt)
                    a[sp][ks][mt] = *(const bf16x8*)&As[rb][(wm + sp * 32 + mt * 16 + lrow) * 64 + kgr];
#pragma unroll
            for (int qn = 0; qn < 2; ++qn)
#pragma unroll
                for (int nt = 0; nt < 2; ++nt)
                    b[qn][ks][nt] = *(const bf16x8*)&Bs[rb][(wn + qn * 32 + nt * 16 + lrow) * 64 + kgr];
        }
        // stage next-next tile's 6 loads (issue-early; land under MFMA)
        if (st) {
            STAGE_A(sb, k2, 0); STAGE_A(sb, k2, 1); STAGE_A(sb, k2, 2); STAGE_A(sb, k2, 3);
            STAGE_B(sb, k2, 0); STAGE_B(sb, k2, 1);
        }
        __builtin_amdgcn_s_barrier();         // reads + loads in flight while waiting
        __builtin_amdgcn_s_setprio(1);
#pragma unroll
        for (int ks = 0; ks < 2; ++ks)        // ks outer: 16 independent MFMA per k-step
#pragma unroll
            for (int sp = 0; sp < 2; ++sp)
#pragma unroll
                for (int qn = 0; qn < 2; ++qn)
#pragma unroll
                    for (int mt = 0; mt < 2; ++mt)
#pragma unroll
                        for (int nt = 0; nt < 2; ++nt)
                            acc[sp * 2 + mt][qn * 2 + nt] = __builtin_amdgcn_mfma_f32_16x16x32_bf16(
                                a[sp][ks][mt], b[qn][ks][nt], acc[sp * 2 + mt][qn * 2 + nt], 0, 0, 0);
        __builtin_amdgcn_s_setprio(0);
        // tile-boundary wait: next tile's 6 loads (oldest outstanding) landed;
        // newest 6 (tile t+2) stay in flight across the barrier.
        if (st)              asm volatile("s_waitcnt vmcnt(6)" ::: "memory");
        else if (t + 1 < NT) asm volatile("s_waitcnt vmcnt(0)" ::: "memory");
        __builtin_amdgcn_s_barrier();
        rb = (rb == 2) ? 0 : rb + 1;
    }
#undef STAGE_A
#undef STAGE_B

    const int crow = (lane >> 4) * 4;
    const int ccol = lane & 15;
#pragma unroll
    for (int nt = 0; nt < 4; ++nt) {
        const int j = h0 + wn + nt * 16 + ccol;
        const float bv = b1[j];
#pragma unroll
        for (int mt = 0; mt < 4; ++mt) {
#pragma unroll
            for (int r = 0; r < 4; ++r) {
                const int s = s0 + wm + mt * 16 + crow + r;
                const float v = acc[mt][nt][r] + bv;
                Hout[(size_t)s * H_DIM + j] = (bf16_t)fmaxf(v, 0.f);
            }
        }
    }
}

// ---------------- Phase 2: feats = H @ w2^T + b2 (fp32 out), MFMA ----------
// M=128 x N=32, BK=64 (16 iters). A via global_load_lds; B converted fp32->bf16
// in-kernel. 64-wide rows: swizzle kg ^ (row&7).
__global__ __launch_bounds__(256) void feats_mfma(const bf16_t* __restrict__ Hb,
                                                  const float* __restrict__ w2,
                                                  const float* __restrict__ b2,
                                                  float* __restrict__ F) {
    __shared__ bf16_t As[128 * 64];
    __shared__ bf16_t Bs[32 * 64];
    const int tid  = threadIdx.x;
    const int wave = tid >> 6, lane = tid & 63;
    const int s0 = blockIdx.x * 128;
    const int wm = wave * 32;

    // A staging: chunk i*256+tid -> row = i*32 + (tid>>3), kg = tid&7
    const int arow = tid >> 3;
    const int akgs = (tid & 7) ^ (arow & 7);          // (i*32+arow)&7 == arow&7
    const bf16_t* gA = Hb + (size_t)(s0 + arow) * H_DIM + akgs * 8;
    // B staging: row = tid>>3 (0..31), kg = tid&7
    const int brow = tid >> 3;
    const int bkgs = (tid & 7) ^ (brow & 7);
    const float* wp = w2 + (size_t)brow * H_DIM + bkgs * 8;
    bf16_t* lB = &Bs[tid * 8];

    const int lrow = lane & 15;

    f32x4 acc[2][2] = {};
    for (int k0 = 0; k0 < H_DIM; k0 += 64) {
#pragma unroll
        for (int i = 0; i < 4; ++i)
            async_copy16(gA + (size_t)i * 32 * H_DIM + k0, &As[(tid + i * 256) * 8]);
        const float4 x0 = *(const float4*)(wp + k0);
        const float4 x1 = *(const float4*)(wp + k0 + 4);
        bf16x8 bb = {(bf16_t)x0.x, (bf16_t)x0.y, (bf16_t)x0.z, (bf16_t)x0.w,
                     (bf16_t)x1.x, (bf16_t)x1.y, (bf16_t)x1.z, (bf16_t)x1.w};
        *(bf16x8*)lB = bb;
        __syncthreads();
#pragma unroll
        for (int ks = 0; ks < 2; ++ks) {
            const int kq = ((ks * 4 + (lane >> 4)) ^ (lrow & 7)) * 8;
            bf16x8 a[2], b[2];
#pragma unroll
            for (int mt = 0; mt < 2; ++mt)
                a[mt] = *(const bf16x8*)&As[(wm + mt * 16 + lrow) * 64 + kq];
#pragma unroll
            for (int nt = 0; nt < 2; ++nt)
                b[nt] = *(const bf16x8*)&Bs[(nt * 16 + lrow) * 64 + kq];
#pragma unroll
            for (int mt = 0; mt < 2; ++mt)
#pragma unroll
                for (int nt = 0; nt < 2; ++nt)
                    acc[mt][nt] = __builtin_amdgcn_mfma_f32_16x16x32_bf16(a[mt], b[nt], acc[mt][nt], 0, 0, 0);
        }
        __syncthreads();
    }
    const int crow = (lane >> 4) * 4;
    const int ccol = lane & 15;
#pragma unroll
    for (int nt = 0; nt < 2; ++nt) {
        const int j = nt * 16 + ccol;
        const float bv = b2[j];
#pragma unroll
        for (int mt = 0; mt < 2; ++mt) {
#pragma unroll
            for (int r = 0; r < 4; ++r) {
                const int s = s0 + wm + mt * 16 + crow + r;
                F[(size_t)s * T_TAG + j] = acc[mt][nt][r] + bv;
            }
        }
    }
}

// ---------------- CRF pass A: per-chunk matrix-chain products --------------
// v round-trips through a per-wave LDS slice (wave-lockstep => barrier-free):
// 1 ds_write + 8 broadcast ds_read_b128 per step instead of 32 bpermutes.
__global__ __launch_bounds__(256) void crfA(const float* __restrict__ F,
                                            const float* __restrict__ trans,
                                            float* __restrict__ QT,
                                            float* __restrict__ sigma) {
    __shared__ float fl[L_CHUNK * 32];
    __shared__ float vb[4][2][32];
    const int c    = blockIdx.x >> 2;
    const int tid  = threadIdx.x;
    const int wave = tid >> 6;
    const int lane = tid & 63;
    const int n    = lane & 31;
    const int pl   = lane >> 5;
    const int p    = ((blockIdx.x & 3) << 3) + (wave << 1) + pl;
    const int s0   = c * L_CHUNK;
    for (int i = tid; i < L_CHUNK * 32; i += 256) fl[i] = F[(size_t)s0 * 32 + i];
    __syncthreads();

    float et[32];
#pragma unroll
    for (int k = 0; k < 32; ++k) et[k] = __expf(trans[n * 32 + k]);

    float* vrow = &vb[wave][pl][0];
    float v  = __expf(trans[n * 32 + p] + fl[n]);
    float sg = 0.f;
    for (int s = 1; s < L_CHUNK; ++s) {
        vrow[n] = v;
        __builtin_amdgcn_s_waitcnt(0xC07F);   // lgkmcnt(0): wave-coherent LDS
        float a0 = 0.f, a1 = 0.f, a2 = 0.f, a3 = 0.f;
#pragma unroll
        for (int q = 0; q < 8; ++q) {
            const float4 wv = *(const float4*)&vrow[q * 4];
            a0 = __builtin_fmaf(et[q * 4 + 0], wv.x, a0);
            a1 = __builtin_fmaf(et[q * 4 + 1], wv.y, a1);
            a2 = __builtin_fmaf(et[q * 4 + 2], wv.z, a2);
            a3 = __builtin_fmaf(et[q * 4 + 3], wv.w, a3);
        }
        v = __expf(fl[s * 32 + n]) * ((a0 + a1) + (a2 + a3));
        if ((s & 7) == 7) {
            float m = v;
#pragma unroll
            for (int off = 16; off; off >>= 1) m = fmaxf(m, __shfl_xor(m, off, 32));
            if (m > 0.f) { v *= 1.0f / m; sg += __logf(m); }
        }
    }
    QT[(c * 32 + p) * 32 + n] = v;
    if (n == 0) sigma[c * 32 + p] = sg;
}

// ---------------- CRF pass B: parallel matrix fold ----------------
__global__ __launch_bounds__(1024) void crf_fold(const float* __restrict__ Qin,
                                                 const float* __restrict__ Sin,
                                                 const int fold, const int final,
                                                 float* __restrict__ Qout,
                                                 float* __restrict__ Sout,
                                                 const float* __restrict__ trans,
                                                 const float* __restrict__ F,
                                                 const int* __restrict__ lab,
                                                 float* __restrict__ out) {
    __shared__ float A[32][33];
    __shared__ float M[32][33];
    __shared__ float sgf[32];
    __shared__ float gred[16];
    __shared__ float gold_s;

    const int t = threadIdx.x;
    const int p = t >> 5, n = t & 31;
    const int c0 = blockIdx.x * fold;

    if (final) {
        float ga = 0.f;
        for (int s = t; s < S_LEN; s += 1024) {
            const int tg = lab[s];
            ga += F[(size_t)s * T_TAG + tg];
            const int tp = (s == 0) ? START_TAG : lab[s - 1];
            ga += trans[tg * T_TAG + tp];
        }
        if (t == 0) ga += trans[STOP_TAG * T_TAG + lab[S_LEN - 1]];
#pragma unroll
        for (int off = 32; off; off >>= 1) ga += __shfl_down(ga, off, 64);
        if ((t & 63) == 0) gred[t >> 6] = ga;
    }

    A[n][p] = Qin[(size_t)(c0 * 32 + p) * 32 + n];
    float sA = Sin[c0 * 32 + p];
    float mreg = Qin[(size_t)((c0 + 1) * 32 + p) * 32 + n];

    for (int i = 1; i < fold; ++i) {
        const float sMn = Sin[(c0 + i) * 32 + n];
        float mmax = sMn;
#pragma unroll
        for (int off = 16; off; off >>= 1) mmax = fmaxf(mmax, __shfl_xor(mmax, off, 32));
        const float sMp = Sin[(c0 + i) * 32 + p];
        __syncthreads();
        M[n][p] = mreg * __expf(sMp - mmax);
        if (i + 1 < fold) mreg = Qin[(size_t)((c0 + i + 1) * 32 + p) * 32 + n];
        __syncthreads();
        float acc = 0.f;
#pragma unroll 8
        for (int k = 0; k < 32; ++k)
            acc += M[n][k] * A[k][p];
        float cm = acc;
#pragma unroll
        for (int off = 16; off; off >>= 1) cm = fmaxf(cm, __shfl_xor(cm, off, 32));
        cm = fmaxf(cm, 1e-37f);
        __syncthreads();
        A[n][p] = acc / cm;
        sA = sA + mmax + __logf(cm);
    }
    __syncthreads();

    if (!final) {
        Qout[(size_t)(blockIdx.x * 32 + p) * 32 + n] = A[n][p];
        if (n == 0) Sout[blockIdx.x * 32 + p] = sA;
        return;
    }

    if (n == 0) sgf[p] = sA;
    if (t == 0) {
        float s = 0.f;
#pragma unroll
        for (int i = 0; i < 16; ++i) s += gred[i];
        gold_s = s;
    }
    __syncthreads();
    if (t < 32) {
        float v = A[t][START_TAG] * __expf(trans[STOP_TAG * T_TAG + t]);
#pragma unroll
        for (int off = 16; off; off >>= 1) v += __shfl_xor(v, off, 32);
        if (t == 0) out[0] = sgf[START_TAG] + __logf(v) - gold_s;
    }
}

// ---------------- launch ----------------
extern "C" void kernel_launch(void* const* d_in, const int* in_sizes, int n_in,
                              void* d_out, int out_size, void* d_ws, size_t ws_size,
                              hipStream_t stream) {
    const int*   ctx   = (const int*)d_in[0];
    const float* gz    = (const float*)d_in[1];
    const int*   lab   = (const int*)d_in[2];
    const float* emb   = (const float*)d_in[3];
    const float* w1    = (const float*)d_in[4];
    const float* b1    = (const float*)d_in[5];
    const float* w2    = (const float*)d_in[6];
    const float* b2    = (const float*)d_in[7];
    const float* trans = (const float*)d_in[8];
    float* out = (float*)d_out;

    char* ws = (char*)d_ws;
    bf16_t* Xb  = (bf16_t*)(ws + 0);               // 8192*3456*2 = 56,623,104
    bf16_t* W1b = (bf16_t*)(ws + 56623104);        // 1024*3456*2 =  7,077,888
    bf16_t* Hb  = (bf16_t*)(ws + 63700992);        // 8192*1024*2 = 16,777,216
    float*  F   = (float*)(ws + 80478208);         // 8192*32*4   =  1,048,576
    float*  QT  = (float*)(ws + 81526784);         // 64*32*32*4  =    262,144
    float*  sg  = (float*)(ws + 81788928);         // 64*32*4     =      8,192
    // fold temporaries overlay the Xb region (consumed after gemm1):
    float*  Q1  = (float*)(ws + 65536);            // 16*32*32*4  =     65,536
    float*  S1  = (float*)(ws + 131072);           // 16*32*4     =      2,048

    build_x<<<S_LEN, 256, 0, stream>>>(ctx, gz, emb, Xb);
    build_w1b<<<H_DIM, 256, 0, stream>>>(w1, W1b);
    gemm1<<<dim3(S_LEN / 256, H_DIM / 128), 512, 0, stream>>>(Xb, W1b, b1, Hb);
    feats_mfma<<<S_LEN / 128, 256, 0, stream>>>(Hb, w2, b2, F);
    crfA<<<K_CHUNKS * 4, 256, 0, stream>>>(F, trans, QT, sg);
    crf_fold<<<16, 1024, 0, stream>>>(QT, sg, 4, 0, Q1, S1, trans, F, lab, out);
    crf_fold<<<1, 1024, 0, stream>>>(Q1, S1, 16, 1, nullptr, nullptr, trans, F, lab, out);
}

// Round 6
// 264.518 us; speedup vs baseline: 1.1053x; 1.0556x over previous
//
#include <hip/hip_runtime.h>

#define S_LEN 8192
#define C_CTX 21
#define E_DIM 128
#define G_DIM 36
#define H_DIM 1024
#define T_TAG 32
#define D_RAW 3444          // 21*(128+36)
#define DP 3456             // padded to multiple of 64 (54 K-tiles of 64)
#define START_TAG 30
#define STOP_TAG 31
#define NEGV -10000.0f
#define K_CHUNKS 64
#define L_CHUNK 128         // K_CHUNKS * L_CHUNK == S_LEN

typedef __bf16 bf16_t;
typedef __bf16 bf16x4 __attribute__((ext_vector_type(4)));
typedef __bf16 bf16x8 __attribute__((ext_vector_type(8)));
typedef float  f32x4  __attribute__((ext_vector_type(4)));

__device__ inline void async_copy16(const bf16_t* g, bf16_t* l) {
    __builtin_amdgcn_global_load_lds(
        (const __attribute__((address_space(1))) void*)g,
        (__attribute__((address_space(3))) void*)l, 16, 0, 0);
}

// ---------------- Phase 0: materialize padded bf16 X and W1 (one kernel) ----
// blocks 0..H_DIM-1: W1 rows; blocks H_DIM..H_DIM+S_LEN-1: X rows.
__global__ void build_all(const int* __restrict__ ctx, const float* __restrict__ gz,
                          const float* __restrict__ emb, const float* __restrict__ w1,
                          bf16_t* __restrict__ X, bf16_t* __restrict__ W) {
    const int b = blockIdx.x;
    if (b < H_DIM) {
        const int h = b;
        for (int g = threadIdx.x; g < DP / 4; g += 256) {
            float4 v = {0.f, 0.f, 0.f, 0.f};
            if (g < D_RAW / 4) v = *(const float4*)&w1[(size_t)h * D_RAW + g * 4];
            bf16x4 o = {(bf16_t)v.x, (bf16_t)v.y, (bf16_t)v.z, (bf16_t)v.w};
            *(bf16x4*)&W[(size_t)h * DP + g * 4] = o;
        }
    } else {
        const int s = b - H_DIM;
        for (int g = threadIdx.x; g < DP / 4; g += 256) {   // 864 groups
            float4 v = {0.f, 0.f, 0.f, 0.f};
            if (g < D_RAW / 4) {                             // 861 real groups
                const int c  = g / 41;
                const int rg = g - c * 41;                   // 0..40
                if (rg < 32) v = *(const float4*)&emb[(size_t)ctx[s * C_CTX + c] * E_DIM + rg * 4];
                else         v = *(const float4*)&gz[((size_t)s * C_CTX + c) * G_DIM + (rg - 32) * 4];
            }
            bf16x4 o = {(bf16_t)v.x, (bf16_t)v.y, (bf16_t)v.z, (bf16_t)v.w};
            *(bf16x4*)&X[(size_t)s * DP + g * 4] = o;
        }
    }
}

// ---------------- Phase 1: h = relu(X @ W1^T + b1); Fp = h @ w2_slice^T ----
// Main loop: 256x128 tile, BK=64, 512 threads (8 waves, 4M x 2N), 16x16x32
// MFMA, triple-buffered K-tiles, prefetch distance 2, counted vmcnt(6)
// (never 0 mid-loop), 2 barriers/tile. Verified conflict-free kg^(row&7)
// LDS swizzle (inverse-swizzled global source + linear global_load_lds dest
// + swizzled ds_read).
// FUSED EPILOGUE (replaces the feats_mfma kernel): H-tile (relu, bf16) goes
// to LDS (reusing As, same swizzle), w2 slice (32x128) is staged to LDS, and
// a 16-MFMA mini-GEMM per wave produces this block's K-partial of
// F = H @ w2^T, written to Fp[bj][s][t] (b2 folded into partial bj==7).
// Removes the Hb 16.7MB write + 16.7MB read and one kernel launch.
__global__ __launch_bounds__(512) void gemm1(const bf16_t* __restrict__ X,
                                             const bf16_t* __restrict__ W,
                                             const float* __restrict__ b1,
                                             const float* __restrict__ w2,
                                             const float* __restrict__ b2,
                                             float* __restrict__ Fp) {
    __shared__ bf16_t As[3][256 * 64];   // 3 x 32 KB
    __shared__ bf16_t Bs[3][128 * 64];   // 3 x 16 KB  (total 144 KB, 1 block/CU)
    const int tid  = threadIdx.x;
    const int wave = tid >> 6, lane = tid & 63;
    const int s0 = blockIdx.x * 256, h0 = blockIdx.y * 128;
    const int wm = (wave >> 1) * 64;     // 4 wave-rows
    const int wn = (wave & 1) * 64;      // 2 wave-cols

    const int arow = tid >> 3;                         // 0..63
    const int akg  = (tid & 7) ^ (arow & 7);
    const bf16_t* gA = X + (size_t)(s0 + arow) * DP + akg * 8;
    const bf16_t* gB = W + (size_t)(h0 + arow) * DP + akg * 8;

    const int lrow  = lane & 15;
    const int khalf = lane >> 4;         // 0..3
    const int lr7   = lrow & 7;

#define STAGE_A(buf, k0, i) async_copy16(gA + (size_t)(i) * 64 * DP + (k0), &As[buf][((i) * 512 + tid) * 8])
#define STAGE_B(buf, k0, i) async_copy16(gB + (size_t)(i) * 64 * DP + (k0), &Bs[buf][((i) * 512 + tid) * 8])

    // prologue: tiles 0 and 1 (12 loads in flight)
    STAGE_A(0, 0, 0); STAGE_A(0, 0, 1); STAGE_A(0, 0, 2); STAGE_A(0, 0, 3);
    STAGE_B(0, 0, 0); STAGE_B(0, 0, 1);
    STAGE_A(1, 64, 0); STAGE_A(1, 64, 1); STAGE_A(1, 64, 2); STAGE_A(1, 64, 3);
    STAGE_B(1, 64, 0); STAGE_B(1, 64, 1);
    asm volatile("s_waitcnt vmcnt(6)" ::: "memory");   // tile 0 landed; tile 1 in flight
    __builtin_amdgcn_s_barrier();

    f32x4 acc[4][4] = {};
    const int NT = DP / 64;              // 54
    int rb = 0;
    for (int t = 0; t < NT; ++t) {
        const int  sb = (rb == 0) ? 2 : rb - 1;   // (t+2)%3: buffer of tile t-1, reads done
        const int  k2 = (t + 2) * 64;
        const bool st = (t + 2) < NT;

        // all register fragments for this K-tile: 8 A + 8 B = 16 ds_read_b128
        bf16x8 a[2][2][2];     // [sp][ks][mt]
        bf16x8 b[2][2][2];     // [qn][ks][nt]
#pragma unroll
        for (int ks = 0; ks < 2; ++ks) {
            const int kgr = ((ks * 4 + khalf) ^ lr7) * 8;
#pragma unroll
            for (int sp = 0; sp < 2; ++sp)
#pragma unroll
                for (int mt = 0; mt < 2; ++mt)
                    a[sp][ks][mt] = *(const bf16x8*)&As[rb][(wm + sp * 32 + mt * 16 + lrow) * 64 + kgr];
#pragma unroll
            for (int qn = 0; qn < 2; ++qn)
#pragma unroll
                for (int nt = 0; nt < 2; ++nt)
                    b[qn][ks][nt] = *(const bf16x8*)&Bs[rb][(wn + qn * 32 + nt * 16 + lrow) * 64 + kgr];
        }
        if (st) {
            STAGE_A(sb, k2, 0); STAGE_A(sb, k2, 1); STAGE_A(sb, k2, 2); STAGE_A(sb, k2, 3);
            STAGE_B(sb, k2, 0); STAGE_B(sb, k2, 1);
        }
        __builtin_amdgcn_s_barrier();         // reads + loads in flight while waiting
        __builtin_amdgcn_s_setprio(1);
#pragma unroll
        for (int ks = 0; ks < 2; ++ks)
#pragma unroll
            for (int sp = 0; sp < 2; ++sp)
#pragma unroll
                for (int qn = 0; qn < 2; ++qn)
#pragma unroll
                    for (int mt = 0; mt < 2; ++mt)
#pragma unroll
                        for (int nt = 0; nt < 2; ++nt)
                            acc[sp * 2 + mt][qn * 2 + nt] = __builtin_amdgcn_mfma_f32_16x16x32_bf16(
                                a[sp][ks][mt], b[qn][ks][nt], acc[sp * 2 + mt][qn * 2 + nt], 0, 0, 0);
        __builtin_amdgcn_s_setprio(0);
        if (st)              asm volatile("s_waitcnt vmcnt(6)" ::: "memory");
        else if (t + 1 < NT) asm volatile("s_waitcnt vmcnt(0)" ::: "memory");
        __builtin_amdgcn_s_barrier();
        rb = (rb == 2) ? 0 : rb + 1;
    }
#undef STAGE_A
#undef STAGE_B

    // ---- fused feats epilogue ----
    // After the final barrier no wave touches As/Bs: reuse them.
    bf16_t* Hl = &As[0][0];              // 256 x 128 bf16 (64 KB, spans As[0..1]), swizzled rows
    bf16_t* Wl = &Bs[0][0];              // 32 x 128 bf16 (8 KB), swizzled rows

    // stage w2 slice: 32 tags x 128 h (f32 -> bf16), 8 values/thread
    {
        const int t8 = tid >> 4;            // 0..31 tag
        const int hl = tid & 15;            // 0..15 k-group
        const float* wsrc = w2 + (size_t)t8 * H_DIM + h0 + hl * 8;
        const float4 y0 = *(const float4*)wsrc;
        const float4 y1 = *(const float4*)(wsrc + 4);
        bf16x8 wv = {(bf16_t)y0.x, (bf16_t)y0.y, (bf16_t)y0.z, (bf16_t)y0.w,
                     (bf16_t)y1.x, (bf16_t)y1.y, (bf16_t)y1.z, (bf16_t)y1.w};
        *(bf16x8*)&Wl[(t8 * 16 + (hl ^ (t8 & 7))) * 8] = wv;
    }

    // H tile (relu + bf16) -> LDS, swizzled: Hl[s][ (j/8 ^ s&7)*8 + j%8 ]
    const int crow = (lane >> 4) * 4;
    const int ccol = lane & 15;
#pragma unroll
    for (int nt = 0; nt < 4; ++nt) {
        const int jl = wn + nt * 16 + ccol;          // 0..127 local h
        const float bv = b1[h0 + jl];
#pragma unroll
        for (int mt = 0; mt < 4; ++mt) {
#pragma unroll
            for (int r = 0; r < 4; ++r) {
                const int sl = wm + mt * 16 + crow + r;    // 0..255 local s
                const float v = acc[mt][nt][r] + bv;
                Hl[sl * 128 + ((jl >> 3) ^ (sl & 7)) * 8 + (jl & 7)] = (bf16_t)fmaxf(v, 0.f);
            }
        }
    }
    __syncthreads();

    // mini-GEMM: Fpart[s][t] = H[s][:] . w2[t][:] over this 128-h slice.
    // wave handles 32 s-rows x all 32 tags; K=128 in 4 ks-steps of 32.
    f32x4 acc2[2][2] = {};
    const int wm2 = wave * 32;
#pragma unroll
    for (int ks = 0; ks < 4; ++ks) {
        const int slot = ((ks * 4 + khalf) ^ lr7) * 8;
        bf16x8 ah[2], bw[2];
#pragma unroll
        for (int mt = 0; mt < 2; ++mt)
            ah[mt] = *(const bf16x8*)&Hl[(wm2 + mt * 16 + lrow) * 128 + slot];
#pragma unroll
        for (int nt = 0; nt < 2; ++nt)
            bw[nt] = *(const bf16x8*)&Wl[(nt * 16 + lrow) * 128 + slot];
#pragma unroll
        for (int mt = 0; mt < 2; ++mt)
#pragma unroll
            for (int nt = 0; nt < 2; ++nt)
                acc2[mt][nt] = __builtin_amdgcn_mfma_f32_16x16x32_bf16(ah[mt], bw[nt], acc2[mt][nt], 0, 0, 0);
    }
    // store K-partial; fold b2 into the bj==7 partial
    const int bj = h0 >> 7;
#pragma unroll
    for (int nt = 0; nt < 2; ++nt) {
        const int tcol = nt * 16 + ccol;
        const float badd = (bj == 7) ? b2[tcol] : 0.f;
#pragma unroll
        for (int mt = 0; mt < 2; ++mt) {
#pragma unroll
            for (int r = 0; r < 4; ++r) {
                const int sr = s0 + wm2 + mt * 16 + crow + r;
                Fp[((size_t)bj * S_LEN + sr) * T_TAG + tcol] = acc2[mt][nt][r] + badd;
            }
        }
    }
}

// ---------------- CRF pass A: per-chunk matrix-chain products --------------
// Loads F by summing the 8 K-partials (coalesced), writes the summed F for
// crf_fold's gold pass. v round-trips through a per-wave LDS slice
// (wave-lockstep => barrier-free).
__global__ __launch_bounds__(256) void crfA(const float* __restrict__ Fp,
                                            const float* __restrict__ trans,
                                            float* __restrict__ QT,
                                            float* __restrict__ sigma,
                                            float* __restrict__ Fsum) {
    __shared__ float fl[L_CHUNK * 32];
    __shared__ float vb[4][2][32];
    const int c    = blockIdx.x >> 2;
    const int tid  = threadIdx.x;
    const int wave = tid >> 6;
    const int lane = tid & 63;
    const int n    = lane & 31;
    const int pl   = lane >> 5;
    const int p    = ((blockIdx.x & 3) << 3) + (wave << 1) + pl;
    const int s0   = c * L_CHUNK;
    for (int i = tid; i < L_CHUNK * 32; i += 256) {
        const size_t idx = (size_t)s0 * 32 + i;
        float accf = 0.f;
#pragma unroll
        for (int j = 0; j < 8; ++j) accf += Fp[(size_t)j * S_LEN * T_TAG + idx];
        fl[i] = accf;
        Fsum[idx] = accf;
    }
    __syncthreads();

    float et[32];
#pragma unroll
    for (int k = 0; k < 32; ++k) et[k] = __expf(trans[n * 32 + k]);

    float* vrow = &vb[wave][pl][0];
    float v  = __expf(trans[n * 32 + p] + fl[n]);
    float sg = 0.f;
    for (int s = 1; s < L_CHUNK; ++s) {
        vrow[n] = v;
        __builtin_amdgcn_s_waitcnt(0xC07F);   // lgkmcnt(0): wave-coherent LDS
        float a0 = 0.f, a1 = 0.f, a2 = 0.f, a3 = 0.f;
#pragma unroll
        for (int q = 0; q < 8; ++q) {
            const float4 wv = *(const float4*)&vrow[q * 4];
            a0 = __builtin_fmaf(et[q * 4 + 0], wv.x, a0);
            a1 = __builtin_fmaf(et[q * 4 + 1], wv.y, a1);
            a2 = __builtin_fmaf(et[q * 4 + 2], wv.z, a2);
            a3 = __builtin_fmaf(et[q * 4 + 3], wv.w, a3);
        }
        v = __expf(fl[s * 32 + n]) * ((a0 + a1) + (a2 + a3));
        if ((s & 7) == 7) {
            float m = v;
#pragma unroll
            for (int off = 16; off; off >>= 1) m = fmaxf(m, __shfl_xor(m, off, 32));
            if (m > 0.f) { v *= 1.0f / m; sg += __logf(m); }
        }
    }
    QT[(c * 32 + p) * 32 + n] = v;
    if (n == 0) sigma[c * 32 + p] = sg;
}

// ---------------- CRF pass B: parallel matrix fold ----------------
__global__ __launch_bounds__(1024) void crf_fold(const float* __restrict__ Qin,
                                                 const float* __restrict__ Sin,
                                                 const int fold, const int final,
                                                 float* __restrict__ Qout,
                                                 float* __restrict__ Sout,
                                                 const float* __restrict__ trans,
                                                 const float* __restrict__ F,
                                                 const int* __restrict__ lab,
                                                 float* __restrict__ out) {
    __shared__ float A[32][33];
    __shared__ float M[32][33];
    __shared__ float sgf[32];
    __shared__ float gred[16];
    __shared__ float gold_s;

    const int t = threadIdx.x;
    const int p = t >> 5, n = t & 31;
    const int c0 = blockIdx.x * fold;

    if (final) {
        float ga = 0.f;
        for (int s = t; s < S_LEN; s += 1024) {
            const int tg = lab[s];
            ga += F[(size_t)s * T_TAG + tg];
            const int tp = (s == 0) ? START_TAG : lab[s - 1];
            ga += trans[tg * T_TAG + tp];
        }
        if (t == 0) ga += trans[STOP_TAG * T_TAG + lab[S_LEN - 1]];
#pragma unroll
        for (int off = 32; off; off >>= 1) ga += __shfl_down(ga, off, 64);
        if ((t & 63) == 0) gred[t >> 6] = ga;
    }

    A[n][p] = Qin[(size_t)(c0 * 32 + p) * 32 + n];
    float sA = Sin[c0 * 32 + p];
    float mreg = Qin[(size_t)((c0 + 1) * 32 + p) * 32 + n];

    for (int i = 1; i < fold; ++i) {
        const float sMn = Sin[(c0 + i) * 32 + n];
        float mmax = sMn;
#pragma unroll
        for (int off = 16; off; off >>= 1) mmax = fmaxf(mmax, __shfl_xor(mmax, off, 32));
        const float sMp = Sin[(c0 + i) * 32 + p];
        __syncthreads();
        M[n][p] = mreg * __expf(sMp - mmax);
        if (i + 1 < fold) mreg = Qin[(size_t)((c0 + i + 1) * 32 + p) * 32 + n];
        __syncthreads();
        float acc = 0.f;
#pragma unroll 8
        for (int k = 0; k < 32; ++k)
            acc += M[n][k] * A[k][p];
        float cm = acc;
#pragma unroll
        for (int off = 16; off; off >>= 1) cm = fmaxf(cm, __shfl_xor(cm, off, 32));
        cm = fmaxf(cm, 1e-37f);
        __syncthreads();
        A[n][p] = acc / cm;
        sA = sA + mmax + __logf(cm);
    }
    __syncthreads();

    if (!final) {
        Qout[(size_t)(blockIdx.x * 32 + p) * 32 + n] = A[n][p];
        if (n == 0) Sout[blockIdx.x * 32 + p] = sA;
        return;
    }

    if (n == 0) sgf[p] = sA;
    if (t == 0) {
        float s = 0.f;
#pragma unroll
        for (int i = 0; i < 16; ++i) s += gred[i];
        gold_s = s;
    }
    __syncthreads();
    if (t < 32) {
        float v = A[t][START_TAG] * __expf(trans[STOP_TAG * T_TAG + t]);
#pragma unroll
        for (int off = 16; off; off >>= 1) v += __shfl_xor(v, off, 32);
        if (t == 0) out[0] = sgf[START_TAG] + __logf(v) - gold_s;
    }
}

// ---------------- launch ----------------
extern "C" void kernel_launch(void* const* d_in, const int* in_sizes, int n_in,
                              void* d_out, int out_size, void* d_ws, size_t ws_size,
                              hipStream_t stream) {
    const int*   ctx   = (const int*)d_in[0];
    const float* gz    = (const float*)d_in[1];
    const int*   lab   = (const int*)d_in[2];
    const float* emb   = (const float*)d_in[3];
    const float* w1    = (const float*)d_in[4];
    const float* b1    = (const float*)d_in[5];
    const float* w2    = (const float*)d_in[6];
    const float* b2    = (const float*)d_in[7];
    const float* trans = (const float*)d_in[8];
    float* out = (float*)d_out;

    char* ws = (char*)d_ws;
    bf16_t* Xb  = (bf16_t*)(ws + 0);               // 8192*3456*2 = 56,623,104
    bf16_t* W1b = (bf16_t*)(ws + 56623104);        // 1024*3456*2 =  7,077,888
    float*  Fp  = (float*)(ws + 63700992);         // 8*8192*32*4 =  8,388,608 (old Hb region)
    float*  F   = (float*)(ws + 80478208);         // 8192*32*4   =  1,048,576 (summed F)
    float*  QT  = (float*)(ws + 81526784);         // 64*32*32*4  =    262,144
    float*  sg  = (float*)(ws + 81788928);         // 64*32*4     =      8,192
    // fold temporaries overlay the Xb region (consumed after gemm1):
    float*  Q1  = (float*)(ws + 65536);            // 16*32*32*4  =     65,536
    float*  S1  = (float*)(ws + 131072);           // 16*32*4     =      2,048

    build_all<<<H_DIM + S_LEN, 256, 0, stream>>>(ctx, gz, emb, w1, Xb, W1b);
    gemm1<<<dim3(S_LEN / 256, H_DIM / 128), 512, 0, stream>>>(Xb, W1b, b1, w2, b2, Fp);
    crfA<<<K_CHUNKS * 4, 256, 0, stream>>>(Fp, trans, QT, sg, F);
    crf_fold<<<16, 1024, 0, stream>>>(QT, sg, 4, 0, Q1, S1, trans, F, lab, out);
    crf_fold<<<1, 1024, 0, stream>>>(Q1, S1, 16, 1, nullptr, nullptr, trans, F, lab, out);
}

// Round 7
// 245.842 us; speedup vs baseline: 1.1892x; 1.0760x over previous
//
#include <hip/hip_runtime.h>

#define S_LEN 8192
#define C_CTX 21
#define E_DIM 128
#define G_DIM 36
#define H_DIM 1024
#define T_TAG 32
#define D_RAW 3444          // 21*(128+36)
#define DP 3456             // emb-first K layout: 21*128=2688 emb | 756 gz | 12 pad
#define GZP 768             // padded gz width
#define START_TAG 30
#define STOP_TAG 31
#define NEGV -10000.0f
#define K_CHUNKS 64
#define L_CHUNK 128         // K_CHUNKS * L_CHUNK == S_LEN

typedef __bf16 bf16_t;
typedef __bf16 bf16x4 __attribute__((ext_vector_type(4)));
typedef __bf16 bf16x8 __attribute__((ext_vector_type(8)));
typedef float  f32x4  __attribute__((ext_vector_type(4)));

__device__ inline void async_copy16(const bf16_t* g, bf16_t* l) {
    __builtin_amdgcn_global_load_lds(
        (const __attribute__((address_space(1))) void*)g,
        (__attribute__((address_space(3))) void*)l, 16, 0, 0);
}

// ---------------- Phase 0: materialize W1b (emb-first K order), Xg, emb_bf --
// blocks 0..1023: W1b rows | 1024..3071: Xg (4 seq rows each) | 3072..3571: emb->bf16
__global__ void build_all(const int* __restrict__ ctx, const float* __restrict__ gz,
                          const float* __restrict__ emb, const float* __restrict__ w1,
                          bf16_t* __restrict__ Xg, bf16_t* __restrict__ W,
                          bf16_t* __restrict__ EB) {
    const int b = blockIdx.x;
    if (b < 1024) {                       // W1b row h, permuted K
        const int h = b;
        for (int g = threadIdx.x; g < DP / 4; g += 256) {
            bf16x4 o;
            if (g < 672) {                // emb region: knew = g*4; c=knew>>7, e=knew&127
                const int knew = g * 4;
                const float4 v = *(const float4*)&w1[(size_t)h * D_RAW + (knew >> 7) * 164 + (knew & 127)];
                o = bf16x4{(bf16_t)v.x, (bf16_t)v.y, (bf16_t)v.z, (bf16_t)v.w};
            } else {                      // gz region: m = g*4-2688 -> c=m/36, j=m%36
                const int m = g * 4 - 2688;
                float t[4];
#pragma unroll
                for (int u = 0; u < 4; ++u) {
                    const int mm = m + u;
                    t[u] = (mm < 756) ? w1[(size_t)h * D_RAW + (mm / 36) * 164 + 128 + (mm % 36)] : 0.f;
                }
                o = bf16x4{(bf16_t)t[0], (bf16_t)t[1], (bf16_t)t[2], (bf16_t)t[3]};
            }
            *(bf16x4*)&W[(size_t)h * DP + g * 4] = o;
        }
    } else if (b < 3072) {                // Xg: packed gz copy + pad (756 -> 768)
        const int s_base = (b - 1024) * 4;
        for (int g = threadIdx.x; g < 4 * 192; g += 256) {
            const int r = g / 192, gg = g - r * 192;
            const int s = s_base + r;
            bf16x4 o = bf16x4{(bf16_t)0.f, (bf16_t)0.f, (bf16_t)0.f, (bf16_t)0.f};
            if (gg < 189) {               // 189*4 = 756 exactly
                const float4 v = *(const float4*)&gz[(size_t)s * 756 + gg * 4];
                o = bf16x4{(bf16_t)v.x, (bf16_t)v.y, (bf16_t)v.z, (bf16_t)v.w};
            }
            *(bf16x4*)&Xg[(size_t)s * GZP + gg * 4] = o;
        }
    } else {                              // emb f32 -> bf16, flat 8000*128
        const size_t base = (size_t)(b - 3072) * 2048;
        for (int g = threadIdx.x; g < 512; g += 256) {
            const float4 v = *(const float4*)&emb[base + g * 4];
            bf16x4 o = bf16x4{(bf16_t)v.x, (bf16_t)v.y, (bf16_t)v.z, (bf16_t)v.w};
            *(bf16x4*)&EB[base + g * 4] = o;
        }
    }
}

// ---------------- Phase 1: h = relu(X @ W1^T + b1); Fp = h @ w2_slice^T ----
// 256x128 tile, BK=64, 512 threads, 16x16x32 MFMA, triple-buffered K-tiles,
// prefetch distance 2, counted vmcnt(6) (never 0 mid-loop), 2 barriers/tile,
// verified conflict-free kg^(row&7) swizzle. NEW: emb-part A-tiles (t<42) are
// gathered DIRECTLY from the bf16 emb table via ctx (LDS u16 cache) — no X
// materialization. ctx lookups are LDS reads (lgkm), so the vmcnt discipline
// is unchanged. gz-part tiles (t>=42) stage linearly from Xg. Fused feats
// epilogue (unchanged from round 6): H -> LDS, w2 slice -> LDS, 16-MFMA
// mini-GEMM -> Fp[bj][s][t], b2 folded into bj==7.
__global__ __launch_bounds__(512) void gemm1(const int* __restrict__ ctx,
                                             const bf16_t* __restrict__ EB,
                                             const bf16_t* __restrict__ Xg,
                                             const bf16_t* __restrict__ W,
                                             const float* __restrict__ b1,
                                             const float* __restrict__ w2,
                                             const float* __restrict__ b2,
                                             float* __restrict__ Fp) {
    __shared__ bf16_t As[3][256 * 64];        // 3 x 32 KB
    __shared__ bf16_t Bs[3][128 * 64];        // 3 x 16 KB
    __shared__ unsigned short ctxs[256 * 21]; // 10.75 KB (total 154.75 KB, 1 block/CU)
    const int tid  = threadIdx.x;
    const int wave = tid >> 6, lane = tid & 63;
    const int s0 = blockIdx.x * 256, h0 = blockIdx.y * 128;
    const int wm = (wave >> 1) * 64;     // 4 wave-rows
    const int wn = (wave & 1) * 64;      // 2 wave-cols

    const int arow = tid >> 3;                         // 0..63
    const int akg  = (tid & 7) ^ (arow & 7);           // inverse-swizzled source k-group
    const bf16_t* gB = W + (size_t)(h0 + arow) * DP + akg * 8;

    const int lrow  = lane & 15;
    const int khalf = lane >> 4;         // 0..3
    const int lr7   = lrow & 7;

#define STAGE_B(buf, k0, i) async_copy16(gB + (size_t)(i) * 64 * DP + (k0), &Bs[buf][((i) * 512 + tid) * 8])

    // ctx table -> LDS (u16): rows s0..s0+255, flat copy
    for (int j = tid; j < 256 * C_CTX; j += 512)
        ctxs[j] = (unsigned short)ctx[s0 * C_CTX + j];
    asm volatile("s_waitcnt lgkmcnt(0)" ::: "memory");
    __builtin_amdgcn_s_barrier();

    // prologue: tiles 0 and 1 (both c=0), 12 loads in flight
    {
        const int cva = ctxs[(arow      ) * 21], cvb = ctxs[(arow +  64) * 21];
        const int cvc = ctxs[(arow + 128) * 21], cvd = ctxs[(arow + 192) * 21];
        const int ea0 = akg * 8;
        async_copy16(EB + (size_t)cva * 128 + ea0, &As[0][(0 * 512 + tid) * 8]);
        async_copy16(EB + (size_t)cvb * 128 + ea0, &As[0][(1 * 512 + tid) * 8]);
        async_copy16(EB + (size_t)cvc * 128 + ea0, &As[0][(2 * 512 + tid) * 8]);
        async_copy16(EB + (size_t)cvd * 128 + ea0, &As[0][(3 * 512 + tid) * 8]);
        STAGE_B(0, 0, 0); STAGE_B(0, 0, 1);
        const int ea1 = 64 + akg * 8;
        async_copy16(EB + (size_t)cva * 128 + ea1, &As[1][(0 * 512 + tid) * 8]);
        async_copy16(EB + (size_t)cvb * 128 + ea1, &As[1][(1 * 512 + tid) * 8]);
        async_copy16(EB + (size_t)cvc * 128 + ea1, &As[1][(2 * 512 + tid) * 8]);
        async_copy16(EB + (size_t)cvd * 128 + ea1, &As[1][(3 * 512 + tid) * 8]);
        STAGE_B(1, 64, 0); STAGE_B(1, 64, 1);
    }
    asm volatile("s_waitcnt vmcnt(6)" ::: "memory");   // tile 0 landed; tile 1 in flight
    __builtin_amdgcn_s_barrier();

    f32x4 acc[4][4] = {};
    const int NT = DP / 64;              // 54 (tiles 0..41 emb, 42..53 gz)
    int rb = 0;
    for (int t = 0; t < NT; ++t) {
        const int  sb = (rb == 0) ? 2 : rb - 1;   // (t+2)%3: buffer of tile t-1, reads done
        const int  tt = t + 2;
        const bool st = tt < NT;
        const bool semb = st && (tt < 42);

        // ctx for the staged tile FIRST (lgkm ops; counted wait won't drain frags)
        int cv0 = 0, cv1 = 0, cv2 = 0, cv3 = 0;
        if (semb) {
            const int c_ = tt >> 1;
            cv0 = ctxs[(arow      ) * 21 + c_];
            cv1 = ctxs[(arow +  64) * 21 + c_];
            cv2 = ctxs[(arow + 128) * 21 + c_];
            cv3 = ctxs[(arow + 192) * 21 + c_];
        }

        // all register fragments for this K-tile: 8 A + 8 B = 16 ds_read_b128
        bf16x8 a[2][2][2];     // [sp][ks][mt]
        bf16x8 b[2][2][2];     // [qn][ks][nt]
#pragma unroll
        for (int ks = 0; ks < 2; ++ks) {
            const int kgr = ((ks * 4 + khalf) ^ lr7) * 8;
#pragma unroll
            for (int sp = 0; sp < 2; ++sp)
#pragma unroll
                for (int mt = 0; mt < 2; ++mt)
                    a[sp][ks][mt] = *(const bf16x8*)&As[rb][(wm + sp * 32 + mt * 16 + lrow) * 64 + kgr];
#pragma unroll
            for (int qn = 0; qn < 2; ++qn)
#pragma unroll
                for (int nt = 0; nt < 2; ++nt)
                    b[qn][ks][nt] = *(const bf16x8*)&Bs[rb][(wn + qn * 32 + nt * 16 + lrow) * 64 + kgr];
        }
        // stage next-next tile's 6 loads (issue-early; land under MFMA)
        if (st) {
            if (semb) {
                const int e0 = (tt & 1) * 64 + akg * 8;
                async_copy16(EB + (size_t)cv0 * 128 + e0, &As[sb][(0 * 512 + tid) * 8]);
                async_copy16(EB + (size_t)cv1 * 128 + e0, &As[sb][(1 * 512 + tid) * 8]);
                async_copy16(EB + (size_t)cv2 * 128 + e0, &As[sb][(2 * 512 + tid) * 8]);
                async_copy16(EB + (size_t)cv3 * 128 + e0, &As[sb][(3 * 512 + tid) * 8]);
            } else {
                const int m0 = (tt - 42) * 64 + akg * 8;
#pragma unroll
                for (int i = 0; i < 4; ++i)
                    async_copy16(Xg + (size_t)(s0 + arow + i * 64) * GZP + m0, &As[sb][(i * 512 + tid) * 8]);
            }
            STAGE_B(sb, tt * 64, 0); STAGE_B(sb, tt * 64, 1);
        }
        __builtin_amdgcn_s_barrier();         // reads + loads in flight while waiting
        __builtin_amdgcn_s_setprio(1);
#pragma unroll
        for (int ks = 0; ks < 2; ++ks)
#pragma unroll
            for (int sp = 0; sp < 2; ++sp)
#pragma unroll
                for (int qn = 0; qn < 2; ++qn)
#pragma unroll
                    for (int mt = 0; mt < 2; ++mt)
#pragma unroll
                        for (int nt = 0; nt < 2; ++nt)
                            acc[sp * 2 + mt][qn * 2 + nt] = __builtin_amdgcn_mfma_f32_16x16x32_bf16(
                                a[sp][ks][mt], b[qn][ks][nt], acc[sp * 2 + mt][qn * 2 + nt], 0, 0, 0);
        __builtin_amdgcn_s_setprio(0);
        if (st)              asm volatile("s_waitcnt vmcnt(6)" ::: "memory");
        else if (t + 1 < NT) asm volatile("s_waitcnt vmcnt(0)" ::: "memory");
        __builtin_amdgcn_s_barrier();
        rb = (rb == 2) ? 0 : rb + 1;
    }
#undef STAGE_B

    // ---- fused feats epilogue (unchanged) ----
    bf16_t* Hl = &As[0][0];              // 256 x 128 bf16 (64 KB, spans As[0..1])
    bf16_t* Wl = &Bs[0][0];              // 32 x 128 bf16 (8 KB)

    {
        const int t8 = tid >> 4;            // 0..31 tag
        const int hl = tid & 15;            // 0..15 k-group
        const float* wsrc = w2 + (size_t)t8 * H_DIM + h0 + hl * 8;
        const float4 y0 = *(const float4*)wsrc;
        const float4 y1 = *(const float4*)(wsrc + 4);
        bf16x8 wv = {(bf16_t)y0.x, (bf16_t)y0.y, (bf16_t)y0.z, (bf16_t)y0.w,
                     (bf16_t)y1.x, (bf16_t)y1.y, (bf16_t)y1.z, (bf16_t)y1.w};
        *(bf16x8*)&Wl[(t8 * 16 + (hl ^ (t8 & 7))) * 8] = wv;
    }

    const int crow = (lane >> 4) * 4;
    const int ccol = lane & 15;
#pragma unroll
    for (int nt = 0; nt < 4; ++nt) {
        const int jl = wn + nt * 16 + ccol;          // 0..127 local h
        const float bv = b1[h0 + jl];
#pragma unroll
        for (int mt = 0; mt < 4; ++mt) {
#pragma unroll
            for (int r = 0; r < 4; ++r) {
                const int sl = wm + mt * 16 + crow + r;    // 0..255 local s
                const float v = acc[mt][nt][r] + bv;
                Hl[sl * 128 + ((jl >> 3) ^ (sl & 7)) * 8 + (jl & 7)] = (bf16_t)fmaxf(v, 0.f);
            }
        }
    }
    __syncthreads();

    f32x4 acc2[2][2] = {};
    const int wm2 = wave * 32;
#pragma unroll
    for (int ks = 0; ks < 4; ++ks) {
        const int slot = ((ks * 4 + khalf) ^ lr7) * 8;
        bf16x8 ah[2], bw[2];
#pragma unroll
        for (int mt = 0; mt < 2; ++mt)
            ah[mt] = *(const bf16x8*)&Hl[(wm2 + mt * 16 + lrow) * 128 + slot];
#pragma unroll
        for (int nt = 0; nt < 2; ++nt)
            bw[nt] = *(const bf16x8*)&Wl[(nt * 16 + lrow) * 128 + slot];
#pragma unroll
        for (int mt = 0; mt < 2; ++mt)
#pragma unroll
            for (int nt = 0; nt < 2; ++nt)
                acc2[mt][nt] = __builtin_amdgcn_mfma_f32_16x16x32_bf16(ah[mt], bw[nt], acc2[mt][nt], 0, 0, 0);
    }
    const int bj = h0 >> 7;
#pragma unroll
    for (int nt = 0; nt < 2; ++nt) {
        const int tcol = nt * 16 + ccol;
        const float badd = (bj == 7) ? b2[tcol] : 0.f;
#pragma unroll
        for (int mt = 0; mt < 2; ++mt) {
#pragma unroll
            for (int r = 0; r < 4; ++r) {
                const int sr = s0 + wm2 + mt * 16 + crow + r;
                Fp[((size_t)bj * S_LEN + sr) * T_TAG + tcol] = acc2[mt][nt][r] + badd;
            }
        }
    }
}

// ---------------- CRF pass A: per-chunk matrix-chain products --------------
__global__ __launch_bounds__(256) void crfA(const float* __restrict__ Fp,
                                            const float* __restrict__ trans,
                                            float* __restrict__ QT,
                                            float* __restrict__ sigma,
                                            float* __restrict__ Fsum) {
    __shared__ float fl[L_CHUNK * 32];
    __shared__ float vb[4][2][32];
    const int c    = blockIdx.x >> 2;
    const int tid  = threadIdx.x;
    const int wave = tid >> 6;
    const int lane = tid & 63;
    const int n    = lane & 31;
    const int pl   = lane >> 5;
    const int p    = ((blockIdx.x & 3) << 3) + (wave << 1) + pl;
    const int s0   = c * L_CHUNK;
    for (int i = tid; i < L_CHUNK * 32; i += 256) {
        const size_t idx = (size_t)s0 * 32 + i;
        float accf = 0.f;
#pragma unroll
        for (int j = 0; j < 8; ++j) accf += Fp[(size_t)j * S_LEN * T_TAG + idx];
        fl[i] = accf;
        Fsum[idx] = accf;
    }
    __syncthreads();

    float et[32];
#pragma unroll
    for (int k = 0; k < 32; ++k) et[k] = __expf(trans[n * 32 + k]);

    float* vrow = &vb[wave][pl][0];
    float v  = __expf(trans[n * 32 + p] + fl[n]);
    float sg = 0.f;
    for (int s = 1; s < L_CHUNK; ++s) {
        vrow[n] = v;
        __builtin_amdgcn_s_waitcnt(0xC07F);   // lgkmcnt(0): wave-coherent LDS
        float a0 = 0.f, a1 = 0.f, a2 = 0.f, a3 = 0.f;
#pragma unroll
        for (int q = 0; q < 8; ++q) {
            const float4 wv = *(const float4*)&vrow[q * 4];
            a0 = __builtin_fmaf(et[q * 4 + 0], wv.x, a0);
            a1 = __builtin_fmaf(et[q * 4 + 1], wv.y, a1);
            a2 = __builtin_fmaf(et[q * 4 + 2], wv.z, a2);
            a3 = __builtin_fmaf(et[q * 4 + 3], wv.w, a3);
        }
        v = __expf(fl[s * 32 + n]) * ((a0 + a1) + (a2 + a3));
        if ((s & 7) == 7) {
            float m = v;
#pragma unroll
            for (int off = 16; off; off >>= 1) m = fmaxf(m, __shfl_xor(m, off, 32));
            if (m > 0.f) { v *= 1.0f / m; sg += __logf(m); }
        }
    }
    QT[(c * 32 + p) * 32 + n] = v;
    if (n == 0) sigma[c * 32 + p] = sg;
}

// ---------------- CRF pass B: parallel matrix fold ----------------
__global__ __launch_bounds__(1024) void crf_fold(const float* __restrict__ Qin,
                                                 const float* __restrict__ Sin,
                                                 const int fold, const int final,
                                                 float* __restrict__ Qout,
                                                 float* __restrict__ Sout,
                                                 const float* __restrict__ trans,
                                                 const float* __restrict__ F,
                                                 const int* __restrict__ lab,
                                                 float* __restrict__ out) {
    __shared__ float A[32][33];
    __shared__ float M[32][33];
    __shared__ float sgf[32];
    __shared__ float gred[16];
    __shared__ float gold_s;

    const int t = threadIdx.x;
    const int p = t >> 5, n = t & 31;
    const int c0 = blockIdx.x * fold;

    if (final) {
        float ga = 0.f;
        for (int s = t; s < S_LEN; s += 1024) {
            const int tg = lab[s];
            ga += F[(size_t)s * T_TAG + tg];
            const int tp = (s == 0) ? START_TAG : lab[s - 1];
            ga += trans[tg * T_TAG + tp];
        }
        if (t == 0) ga += trans[STOP_TAG * T_TAG + lab[S_LEN - 1]];
#pragma unroll
        for (int off = 32; off; off >>= 1) ga += __shfl_down(ga, off, 64);
        if ((t & 63) == 0) gred[t >> 6] = ga;
    }

    A[n][p] = Qin[(size_t)(c0 * 32 + p) * 32 + n];
    float sA = Sin[c0 * 32 + p];
    float mreg = Qin[(size_t)((c0 + 1) * 32 + p) * 32 + n];

    for (int i = 1; i < fold; ++i) {
        const float sMn = Sin[(c0 + i) * 32 + n];
        float mmax = sMn;
#pragma unroll
        for (int off = 16; off; off >>= 1) mmax = fmaxf(mmax, __shfl_xor(mmax, off, 32));
        const float sMp = Sin[(c0 + i) * 32 + p];
        __syncthreads();
        M[n][p] = mreg * __expf(sMp - mmax);
        if (i + 1 < fold) mreg = Qin[(size_t)((c0 + i + 1) * 32 + p) * 32 + n];
        __syncthreads();
        float acc = 0.f;
#pragma unroll 8
        for (int k = 0; k < 32; ++k)
            acc += M[n][k] * A[k][p];
        float cm = acc;
#pragma unroll
        for (int off = 16; off; off >>= 1) cm = fmaxf(cm, __shfl_xor(cm, off, 32));
        cm = fmaxf(cm, 1e-37f);
        __syncthreads();
        A[n][p] = acc / cm;
        sA = sA + mmax + __logf(cm);
    }
    __syncthreads();

    if (!final) {
        Qout[(size_t)(blockIdx.x * 32 + p) * 32 + n] = A[n][p];
        if (n == 0) Sout[blockIdx.x * 32 + p] = sA;
        return;
    }

    if (n == 0) sgf[p] = sA;
    if (t == 0) {
        float s = 0.f;
#pragma unroll
        for (int i = 0; i < 16; ++i) s += gred[i];
        gold_s = s;
    }
    __syncthreads();
    if (t < 32) {
        float v = A[t][START_TAG] * __expf(trans[STOP_TAG * T_TAG + t]);
#pragma unroll
        for (int off = 16; off; off >>= 1) v += __shfl_xor(v, off, 32);
        if (t == 0) out[0] = sgf[START_TAG] + __logf(v) - gold_s;
    }
}

// ---------------- launch ----------------
extern "C" void kernel_launch(void* const* d_in, const int* in_sizes, int n_in,
                              void* d_out, int out_size, void* d_ws, size_t ws_size,
                              hipStream_t stream) {
    const int*   ctx   = (const int*)d_in[0];
    const float* gz    = (const float*)d_in[1];
    const int*   lab   = (const int*)d_in[2];
    const float* emb   = (const float*)d_in[3];
    const float* w1    = (const float*)d_in[4];
    const float* b1    = (const float*)d_in[5];
    const float* w2    = (const float*)d_in[6];
    const float* b2    = (const float*)d_in[7];
    const float* trans = (const float*)d_in[8];
    float* out = (float*)d_out;

    char* ws = (char*)d_ws;
    bf16_t* W1b = (bf16_t*)(ws + 0);               // 1024*3456*2 =  7,077,888
    bf16_t* EB  = (bf16_t*)(ws + 7077888);         // 8000*128*2  =  2,048,000
    bf16_t* Xg  = (bf16_t*)(ws + 9126400);         // 8192*768*2  = 12,582,912
    float*  Fp  = (float*)(ws + 21709312);         // 8*8192*32*4 =  8,388,608
    float*  F   = (float*)(ws + 30097920);         // 8192*32*4   =  1,048,576
    float*  QT  = (float*)(ws + 31146496);         // 64*32*32*4  =    262,144
    float*  sg  = (float*)(ws + 31408640);         // 64*32*4     =      8,192
    float*  Q1  = (float*)(ws + 31416832);         // 8*32*32*4   =     32,768
    float*  S1  = (float*)(ws + 31449600);         // 8*32*4      =      1,024

    build_all<<<3572, 256, 0, stream>>>(ctx, gz, emb, w1, Xg, W1b, EB);
    gemm1<<<dim3(S_LEN / 256, H_DIM / 128), 512, 0, stream>>>(ctx, EB, Xg, W1b, b1, w2, b2, Fp);
    crfA<<<K_CHUNKS * 4, 256, 0, stream>>>(Fp, trans, QT, sg, F);
    crf_fold<<<8, 1024, 0, stream>>>(QT, sg, 8, 0, Q1, S1, trans, F, lab, out);
    crf_fold<<<1, 1024, 0, stream>>>(Q1, S1, 8, 1, nullptr, nullptr, trans, F, lab, out);
}

// Round 8
// 240.878 us; speedup vs baseline: 1.2137x; 1.0206x over previous
//
#include <hip/hip_runtime.h>

#define S_LEN 8192
#define C_CTX 21
#define E_DIM 128
#define G_DIM 36
#define H_DIM 1024
#define T_TAG 32
#define D_RAW 3444          // 21*(128+36)
#define DP 3456             // emb-first K layout: 21*128=2688 emb | 756 gz | 12 pad
#define GZP 768             // padded gz width
#define START_TAG 30
#define STOP_TAG 31
#define NEGV -10000.0f
#define K_CHUNKS 64
#define L_CHUNK 128         // K_CHUNKS * L_CHUNK == S_LEN

typedef __bf16 bf16_t;
typedef __bf16 bf16x4 __attribute__((ext_vector_type(4)));
typedef __bf16 bf16x8 __attribute__((ext_vector_type(8)));
typedef float  f32x4  __attribute__((ext_vector_type(4)));

__device__ inline void async_copy16(const bf16_t* g, bf16_t* l) {
    __builtin_amdgcn_global_load_lds(
        (const __attribute__((address_space(1))) void*)g,
        (__attribute__((address_space(3))) void*)l, 16, 0, 0);
}

// ---------------- Phase 0: materialize W1b (emb-first K order), Xg, emb_bf --
// blocks 0..1023: W1b rows | 1024..3071: Xg (4 seq rows each) | 3072..3571: emb->bf16
__global__ void build_all(const int* __restrict__ ctx, const float* __restrict__ gz,
                          const float* __restrict__ emb, const float* __restrict__ w1,
                          bf16_t* __restrict__ Xg, bf16_t* __restrict__ W,
                          bf16_t* __restrict__ EB) {
    const int b = blockIdx.x;
    if (b < 1024) {                       // W1b row h, permuted K
        const int h = b;
        for (int g = threadIdx.x; g < DP / 4; g += 256) {
            bf16x4 o;
            if (g < 672) {                // emb region: knew = g*4; c=knew>>7, e=knew&127
                const int knew = g * 4;
                const float4 v = *(const float4*)&w1[(size_t)h * D_RAW + (knew >> 7) * 164 + (knew & 127)];
                o = bf16x4{(bf16_t)v.x, (bf16_t)v.y, (bf16_t)v.z, (bf16_t)v.w};
            } else {                      // gz region: m = g*4-2688 -> c=m/36, j=m%36
                const int m = g * 4 - 2688;
                float t[4];
#pragma unroll
                for (int u = 0; u < 4; ++u) {
                    const int mm = m + u;
                    t[u] = (mm < 756) ? w1[(size_t)h * D_RAW + (mm / 36) * 164 + 128 + (mm % 36)] : 0.f;
                }
                o = bf16x4{(bf16_t)t[0], (bf16_t)t[1], (bf16_t)t[2], (bf16_t)t[3]};
            }
            *(bf16x4*)&W[(size_t)h * DP + g * 4] = o;
        }
    } else if (b < 3072) {                // Xg: packed gz copy + pad (756 -> 768)
        const int s_base = (b - 1024) * 4;
        for (int g = threadIdx.x; g < 4 * 192; g += 256) {
            const int r = g / 192, gg = g - r * 192;
            const int s = s_base + r;
            bf16x4 o = bf16x4{(bf16_t)0.f, (bf16_t)0.f, (bf16_t)0.f, (bf16_t)0.f};
            if (gg < 189) {               // 189*4 = 756 exactly
                const float4 v = *(const float4*)&gz[(size_t)s * 756 + gg * 4];
                o = bf16x4{(bf16_t)v.x, (bf16_t)v.y, (bf16_t)v.z, (bf16_t)v.w};
            }
            *(bf16x4*)&Xg[(size_t)s * GZP + gg * 4] = o;
        }
    } else {                              // emb f32 -> bf16, flat 8000*128
        const size_t base = (size_t)(b - 3072) * 2048;
        for (int g = threadIdx.x; g < 512; g += 256) {
            const float4 v = *(const float4*)&emb[base + g * 4];
            bf16x4 o = bf16x4{(bf16_t)v.x, (bf16_t)v.y, (bf16_t)v.z, (bf16_t)v.w};
            *(bf16x4*)&EB[base + g * 4] = o;
        }
    }
}

// ---------------- Phase 1: h = relu(X @ W1^T + b1); Fp = h @ w2_slice^T ----
// (unchanged from round 7 — verified). 256x128 tile, BK=64, triple-buffered,
// counted vmcnt(6), emb gather from EB via ctx LDS cache, fused feats epilogue.
__global__ __launch_bounds__(512) void gemm1(const int* __restrict__ ctx,
                                             const bf16_t* __restrict__ EB,
                                             const bf16_t* __restrict__ Xg,
                                             const bf16_t* __restrict__ W,
                                             const float* __restrict__ b1,
                                             const float* __restrict__ w2,
                                             const float* __restrict__ b2,
                                             float* __restrict__ Fp) {
    __shared__ bf16_t As[3][256 * 64];        // 3 x 32 KB
    __shared__ bf16_t Bs[3][128 * 64];        // 3 x 16 KB
    __shared__ unsigned short ctxs[256 * 21]; // 10.75 KB (total 154.75 KB, 1 block/CU)
    const int tid  = threadIdx.x;
    const int wave = tid >> 6, lane = tid & 63;
    const int s0 = blockIdx.x * 256, h0 = blockIdx.y * 128;
    const int wm = (wave >> 1) * 64;     // 4 wave-rows
    const int wn = (wave & 1) * 64;      // 2 wave-cols

    const int arow = tid >> 3;                         // 0..63
    const int akg  = (tid & 7) ^ (arow & 7);           // inverse-swizzled source k-group
    const bf16_t* gB = W + (size_t)(h0 + arow) * DP + akg * 8;

    const int lrow  = lane & 15;
    const int khalf = lane >> 4;         // 0..3
    const int lr7   = lrow & 7;

#define STAGE_B(buf, k0, i) async_copy16(gB + (size_t)(i) * 64 * DP + (k0), &Bs[buf][((i) * 512 + tid) * 8])

    // ctx table -> LDS (u16): rows s0..s0+255, flat copy
    for (int j = tid; j < 256 * C_CTX; j += 512)
        ctxs[j] = (unsigned short)ctx[s0 * C_CTX + j];
    asm volatile("s_waitcnt lgkmcnt(0)" ::: "memory");
    __builtin_amdgcn_s_barrier();

    // prologue: tiles 0 and 1 (both c=0), 12 loads in flight
    {
        const int cva = ctxs[(arow      ) * 21], cvb = ctxs[(arow +  64) * 21];
        const int cvc = ctxs[(arow + 128) * 21], cvd = ctxs[(arow + 192) * 21];
        const int ea0 = akg * 8;
        async_copy16(EB + (size_t)cva * 128 + ea0, &As[0][(0 * 512 + tid) * 8]);
        async_copy16(EB + (size_t)cvb * 128 + ea0, &As[0][(1 * 512 + tid) * 8]);
        async_copy16(EB + (size_t)cvc * 128 + ea0, &As[0][(2 * 512 + tid) * 8]);
        async_copy16(EB + (size_t)cvd * 128 + ea0, &As[0][(3 * 512 + tid) * 8]);
        STAGE_B(0, 0, 0); STAGE_B(0, 0, 1);
        const int ea1 = 64 + akg * 8;
        async_copy16(EB + (size_t)cva * 128 + ea1, &As[1][(0 * 512 + tid) * 8]);
        async_copy16(EB + (size_t)cvb * 128 + ea1, &As[1][(1 * 512 + tid) * 8]);
        async_copy16(EB + (size_t)cvc * 128 + ea1, &As[1][(2 * 512 + tid) * 8]);
        async_copy16(EB + (size_t)cvd * 128 + ea1, &As[1][(3 * 512 + tid) * 8]);
        STAGE_B(1, 64, 0); STAGE_B(1, 64, 1);
    }
    asm volatile("s_waitcnt vmcnt(6)" ::: "memory");   // tile 0 landed; tile 1 in flight
    __builtin_amdgcn_s_barrier();

    f32x4 acc[4][4] = {};
    const int NT = DP / 64;              // 54 (tiles 0..41 emb, 42..53 gz)
    int rb = 0;
    for (int t = 0; t < NT; ++t) {
        const int  sb = (rb == 0) ? 2 : rb - 1;   // (t+2)%3: buffer of tile t-1, reads done
        const int  tt = t + 2;
        const bool st = tt < NT;
        const bool semb = st && (tt < 42);

        // ctx for the staged tile FIRST (lgkm ops; counted wait won't drain frags)
        int cv0 = 0, cv1 = 0, cv2 = 0, cv3 = 0;
        if (semb) {
            const int c_ = tt >> 1;
            cv0 = ctxs[(arow      ) * 21 + c_];
            cv1 = ctxs[(arow +  64) * 21 + c_];
            cv2 = ctxs[(arow + 128) * 21 + c_];
            cv3 = ctxs[(arow + 192) * 21 + c_];
        }

        // all register fragments for this K-tile: 8 A + 8 B = 16 ds_read_b128
        bf16x8 a[2][2][2];     // [sp][ks][mt]
        bf16x8 b[2][2][2];     // [qn][ks][nt]
#pragma unroll
        for (int ks = 0; ks < 2; ++ks) {
            const int kgr = ((ks * 4 + khalf) ^ lr7) * 8;
#pragma unroll
            for (int sp = 0; sp < 2; ++sp)
#pragma unroll
                for (int mt = 0; mt < 2; ++mt)
                    a[sp][ks][mt] = *(const bf16x8*)&As[rb][(wm + sp * 32 + mt * 16 + lrow) * 64 + kgr];
#pragma unroll
            for (int qn = 0; qn < 2; ++qn)
#pragma unroll
                for (int nt = 0; nt < 2; ++nt)
                    b[qn][ks][nt] = *(const bf16x8*)&Bs[rb][(wn + qn * 32 + nt * 16 + lrow) * 64 + kgr];
        }
        // stage next-next tile's 6 loads (issue-early; land under MFMA)
        if (st) {
            if (semb) {
                const int e0 = (tt & 1) * 64 + akg * 8;
                async_copy16(EB + (size_t)cv0 * 128 + e0, &As[sb][(0 * 512 + tid) * 8]);
                async_copy16(EB + (size_t)cv1 * 128 + e0, &As[sb][(1 * 512 + tid) * 8]);
                async_copy16(EB + (size_t)cv2 * 128 + e0, &As[sb][(2 * 512 + tid) * 8]);
                async_copy16(EB + (size_t)cv3 * 128 + e0, &As[sb][(3 * 512 + tid) * 8]);
            } else {
                const int m0 = (tt - 42) * 64 + akg * 8;
#pragma unroll
                for (int i = 0; i < 4; ++i)
                    async_copy16(Xg + (size_t)(s0 + arow + i * 64) * GZP + m0, &As[sb][(i * 512 + tid) * 8]);
            }
            STAGE_B(sb, tt * 64, 0); STAGE_B(sb, tt * 64, 1);
        }
        __builtin_amdgcn_s_barrier();         // reads + loads in flight while waiting
        __builtin_amdgcn_s_setprio(1);
#pragma unroll
        for (int ks = 0; ks < 2; ++ks)
#pragma unroll
            for (int sp = 0; sp < 2; ++sp)
#pragma unroll
                for (int qn = 0; qn < 2; ++qn)
#pragma unroll
                    for (int mt = 0; mt < 2; ++mt)
#pragma unroll
                        for (int nt = 0; nt < 2; ++nt)
                            acc[sp * 2 + mt][qn * 2 + nt] = __builtin_amdgcn_mfma_f32_16x16x32_bf16(
                                a[sp][ks][mt], b[qn][ks][nt], acc[sp * 2 + mt][qn * 2 + nt], 0, 0, 0);
        __builtin_amdgcn_s_setprio(0);
        if (st)              asm volatile("s_waitcnt vmcnt(6)" ::: "memory");
        else if (t + 1 < NT) asm volatile("s_waitcnt vmcnt(0)" ::: "memory");
        __builtin_amdgcn_s_barrier();
        rb = (rb == 2) ? 0 : rb + 1;
    }
#undef STAGE_B

    // ---- fused feats epilogue (unchanged) ----
    bf16_t* Hl = &As[0][0];              // 256 x 128 bf16 (64 KB, spans As[0..1])
    bf16_t* Wl = &Bs[0][0];              // 32 x 128 bf16 (8 KB)

    {
        const int t8 = tid >> 4;            // 0..31 tag
        const int hl = tid & 15;            // 0..15 k-group
        const float* wsrc = w2 + (size_t)t8 * H_DIM + h0 + hl * 8;
        const float4 y0 = *(const float4*)wsrc;
        const float4 y1 = *(const float4*)(wsrc + 4);
        bf16x8 wv = {(bf16_t)y0.x, (bf16_t)y0.y, (bf16_t)y0.z, (bf16_t)y0.w,
                     (bf16_t)y1.x, (bf16_t)y1.y, (bf16_t)y1.z, (bf16_t)y1.w};
        *(bf16x8*)&Wl[(t8 * 16 + (hl ^ (t8 & 7))) * 8] = wv;
    }

    const int crow = (lane >> 4) * 4;
    const int ccol = lane & 15;
#pragma unroll
    for (int nt = 0; nt < 4; ++nt) {
        const int jl = wn + nt * 16 + ccol;          // 0..127 local h
        const float bv = b1[h0 + jl];
#pragma unroll
        for (int mt = 0; mt < 4; ++mt) {
#pragma unroll
            for (int r = 0; r < 4; ++r) {
                const int sl = wm + mt * 16 + crow + r;    // 0..255 local s
                const float v = acc[mt][nt][r] + bv;
                Hl[sl * 128 + ((jl >> 3) ^ (sl & 7)) * 8 + (jl & 7)] = (bf16_t)fmaxf(v, 0.f);
            }
        }
    }
    __syncthreads();

    f32x4 acc2[2][2] = {};
    const int wm2 = wave * 32;
#pragma unroll
    for (int ks = 0; ks < 4; ++ks) {
        const int slot = ((ks * 4 + khalf) ^ lr7) * 8;
        bf16x8 ah[2], bw[2];
#pragma unroll
        for (int mt = 0; mt < 2; ++mt)
            ah[mt] = *(const bf16x8*)&Hl[(wm2 + mt * 16 + lrow) * 128 + slot];
#pragma unroll
        for (int nt = 0; nt < 2; ++nt)
            bw[nt] = *(const bf16x8*)&Wl[(nt * 16 + lrow) * 128 + slot];
#pragma unroll
        for (int mt = 0; mt < 2; ++mt)
#pragma unroll
            for (int nt = 0; nt < 2; ++nt)
                acc2[mt][nt] = __builtin_amdgcn_mfma_f32_16x16x32_bf16(ah[mt], bw[nt], acc2[mt][nt], 0, 0, 0);
    }
    const int bj = h0 >> 7;
#pragma unroll
    for (int nt = 0; nt < 2; ++nt) {
        const int tcol = nt * 16 + ccol;
        const float badd = (bj == 7) ? b2[tcol] : 0.f;
#pragma unroll
        for (int mt = 0; mt < 2; ++mt) {
#pragma unroll
            for (int r = 0; r < 4; ++r) {
                const int sr = s0 + wm2 + mt * 16 + crow + r;
                Fp[((size_t)bj * S_LEN + sr) * T_TAG + tcol] = acc2[mt][nt][r] + badd;
            }
        }
    }
}

// ---------------- CRF pass A: per-chunk matrix-chain products --------------
// ONE chain per 64-lane wave (was 2 chains of 32 lanes): lane (h=lane>>5,
// n=lane&31) computes the half-dot over k in [h*16, h*16+16) (4 broadcast
// ds_read_b128 + 16 FMA), one shfl_xor(32) merges halves — both halves then
// hold v_new[n], so the vrow write is 2-lanes-per-bank (free) and the
// width-32 renorm needs no cross-half step. 512-thread blocks, 8 waves ->
// 2048 waves total = 2 waves/SIMD: the independent waves hide the per-step
// LDS round-trip latency that previously ran at 1 wave/SIMD.
__global__ __launch_bounds__(512) void crfA(const float* __restrict__ Fp,
                                            const float* __restrict__ trans,
                                            float* __restrict__ QT,
                                            float* __restrict__ sigma,
                                            float* __restrict__ Fsum) {
    __shared__ float fl[L_CHUNK * 32];
    __shared__ float vb[8][64];
    const int c    = blockIdx.x >> 2;
    const int tid  = threadIdx.x;
    const int wave = tid >> 6;
    const int lane = tid & 63;
    const int n    = lane & 31;
    const int h    = lane >> 5;                 // half: k in [h*16, h*16+16)
    const int p    = ((blockIdx.x & 3) << 3) + wave;
    const int s0   = c * L_CHUNK;
    for (int i = tid; i < L_CHUNK * 32; i += 512) {
        const size_t idx = (size_t)s0 * 32 + i;
        float accf = 0.f;
#pragma unroll
        for (int j = 0; j < 8; ++j) accf += Fp[(size_t)j * S_LEN * T_TAG + idx];
        fl[i] = accf;
        Fsum[idx] = accf;
    }
    __syncthreads();

    float etl[16];
#pragma unroll
    for (int j = 0; j < 16; ++j) etl[j] = __expf(trans[n * 32 + h * 16 + j]);

    float* vrow = &vb[wave][0];
    float v  = __expf(trans[n * 32 + p] + fl[n]);   // identical in both halves
    float sg = 0.f;
    for (int s = 1; s < L_CHUNK; ++s) {
        vrow[lane] = v;                             // vrow[k] = v[k] (dup at 32+k)
        __builtin_amdgcn_s_waitcnt(0xC07F);         // lgkmcnt(0): wave-coherent LDS
        float a0 = 0.f, a1 = 0.f, a2 = 0.f, a3 = 0.f;
#pragma unroll
        for (int q = 0; q < 4; ++q) {
            const float4 wv = *(const float4*)&vrow[h * 16 + q * 4];
            a0 = __builtin_fmaf(etl[q * 4 + 0], wv.x, a0);
            a1 = __builtin_fmaf(etl[q * 4 + 1], wv.y, a1);
            a2 = __builtin_fmaf(etl[q * 4 + 2], wv.z, a2);
            a3 = __builtin_fmaf(etl[q * 4 + 3], wv.w, a3);
        }
        float part = (a0 + a1) + (a2 + a3);
        part += __shfl_xor(part, 32);               // merge halves: full dot in all lanes
        v = __expf(fl[s * 32 + n]) * part;
        if ((s & 7) == 7) {
            float m = v;
#pragma unroll
            for (int off = 16; off; off >>= 1) m = fmaxf(m, __shfl_xor(m, off, 32));
            if (m > 0.f) { v *= 1.0f / m; sg += __logf(m); }
        }
    }
    if (h == 0) {
        QT[(c * 32 + p) * 32 + n] = v;
        if (n == 0) sigma[c * 32 + p] = sg;
    }
}

// ---------------- CRF pass B: parallel matrix fold ----------------
__global__ __launch_bounds__(1024) void crf_fold(const float* __restrict__ Qin,
                                                 const float* __restrict__ Sin,
                                                 const int fold, const int final,
                                                 float* __restrict__ Qout,
                                                 float* __restrict__ Sout,
                                                 const float* __restrict__ trans,
                                                 const float* __restrict__ F,
                                                 const int* __restrict__ lab,
                                                 float* __restrict__ out) {
    __shared__ float A[32][33];
    __shared__ float M[32][33];
    __shared__ float sgf[32];
    __shared__ float gred[16];
    __shared__ float gold_s;

    const int t = threadIdx.x;
    const int p = t >> 5, n = t & 31;
    const int c0 = blockIdx.x * fold;

    if (final) {
        float ga = 0.f;
        for (int s = t; s < S_LEN; s += 1024) {
            const int tg = lab[s];
            ga += F[(size_t)s * T_TAG + tg];
            const int tp = (s == 0) ? START_TAG : lab[s - 1];
            ga += trans[tg * T_TAG + tp];
        }
        if (t == 0) ga += trans[STOP_TAG * T_TAG + lab[S_LEN - 1]];
#pragma unroll
        for (int off = 32; off; off >>= 1) ga += __shfl_down(ga, off, 64);
        if ((t & 63) == 0) gred[t >> 6] = ga;
    }

    A[n][p] = Qin[(size_t)(c0 * 32 + p) * 32 + n];
    float sA = Sin[c0 * 32 + p];
    float mreg = Qin[(size_t)((c0 + 1) * 32 + p) * 32 + n];

    for (int i = 1; i < fold; ++i) {
        const float sMn = Sin[(c0 + i) * 32 + n];
        float mmax = sMn;
#pragma unroll
        for (int off = 16; off; off >>= 1) mmax = fmaxf(mmax, __shfl_xor(mmax, off, 32));
        const float sMp = Sin[(c0 + i) * 32 + p];
        __syncthreads();
        M[n][p] = mreg * __expf(sMp - mmax);
        if (i + 1 < fold) mreg = Qin[(size_t)((c0 + i + 1) * 32 + p) * 32 + n];
        __syncthreads();
        float acc = 0.f;
#pragma unroll 8
        for (int k = 0; k < 32; ++k)
            acc += M[n][k] * A[k][p];
        float cm = acc;
#pragma unroll
        for (int off = 16; off; off >>= 1) cm = fmaxf(cm, __shfl_xor(cm, off, 32));
        cm = fmaxf(cm, 1e-37f);
        __syncthreads();
        A[n][p] = acc / cm;
        sA = sA + mmax + __logf(cm);
    }
    __syncthreads();

    if (!final) {
        Qout[(size_t)(blockIdx.x * 32 + p) * 32 + n] = A[n][p];
        if (n == 0) Sout[blockIdx.x * 32 + p] = sA;
        return;
    }

    if (n == 0) sgf[p] = sA;
    if (t == 0) {
        float s = 0.f;
#pragma unroll
        for (int i = 0; i < 16; ++i) s += gred[i];
        gold_s = s;
    }
    __syncthreads();
    if (t < 32) {
        float v = A[t][START_TAG] * __expf(trans[STOP_TAG * T_TAG + t]);
#pragma unroll
        for (int off = 16; off; off >>= 1) v += __shfl_xor(v, off, 32);
        if (t == 0) out[0] = sgf[START_TAG] + __logf(v) - gold_s;
    }
}

// ---------------- launch ----------------
extern "C" void kernel_launch(void* const* d_in, const int* in_sizes, int n_in,
                              void* d_out, int out_size, void* d_ws, size_t ws_size,
                              hipStream_t stream) {
    const int*   ctx   = (const int*)d_in[0];
    const float* gz    = (const float*)d_in[1];
    const int*   lab   = (const int*)d_in[2];
    const float* emb   = (const float*)d_in[3];
    const float* w1    = (const float*)d_in[4];
    const float* b1    = (const float*)d_in[5];
    const float* w2    = (const float*)d_in[6];
    const float* b2    = (const float*)d_in[7];
    const float* trans = (const float*)d_in[8];
    float* out = (float*)d_out;

    char* ws = (char*)d_ws;
    bf16_t* W1b = (bf16_t*)(ws + 0);               // 1024*3456*2 =  7,077,888
    bf16_t* EB  = (bf16_t*)(ws + 7077888);         // 8000*128*2  =  2,048,000
    bf16_t* Xg  = (bf16_t*)(ws + 9126400);         // 8192*768*2  = 12,582,912
    float*  Fp  = (float*)(ws + 21709312);         // 8*8192*32*4 =  8,388,608
    float*  F   = (float*)(ws + 30097920);         // 8192*32*4   =  1,048,576
    float*  QT  = (float*)(ws + 31146496);         // 64*32*32*4  =    262,144
    float*  sg  = (float*)(ws + 31408640);         // 64*32*4     =      8,192
    float*  Q1  = (float*)(ws + 31416832);         // 8*32*32*4   =     32,768
    float*  S1  = (float*)(ws + 31449600);         // 8*32*4      =      1,024

    build_all<<<3572, 256, 0, stream>>>(ctx, gz, emb, w1, Xg, W1b, EB);
    gemm1<<<dim3(S_LEN / 256, H_DIM / 128), 512, 0, stream>>>(ctx, EB, Xg, W1b, b1, w2, b2, Fp);
    crfA<<<K_CHUNKS * 4, 512, 0, stream>>>(Fp, trans, QT, sg, F);
    crf_fold<<<8, 1024, 0, stream>>>(QT, sg, 8, 0, Q1, S1, trans, F, lab, out);
    crf_fold<<<1, 1024, 0, stream>>>(Q1, S1, 8, 1, nullptr, nullptr, trans, F, lab, out);
}

// Round 9
// 230.124 us; speedup vs baseline: 1.2705x; 1.0467x over previous
//
#include <hip/hip_runtime.h>

#define S_LEN 8192
#define C_CTX 21
#define E_DIM 128
#define G_DIM 36
#define H_DIM 1024
#define T_TAG 32
#define D_RAW 3444          // 21*(128+36)
#define DP 3456             // emb-first K layout: 21*128=2688 emb | 756 gz | 12 pad
#define GZP 768             // padded gz width
#define START_TAG 30
#define STOP_TAG 31
#define NEGV -10000.0f
#define K_CHUNKS 64
#define L_CHUNK 128         // K_CHUNKS * L_CHUNK == S_LEN

typedef __bf16 bf16_t;
typedef __bf16 bf16x4 __attribute__((ext_vector_type(4)));
typedef __bf16 bf16x8 __attribute__((ext_vector_type(8)));
typedef float  f32x4  __attribute__((ext_vector_type(4)));

__device__ inline void async_copy16(const bf16_t* g, bf16_t* l) {
    __builtin_amdgcn_global_load_lds(
        (const __attribute__((address_space(1))) void*)g,
        (__attribute__((address_space(3))) void*)l, 16, 0, 0);
}

// ---------------- Phase 0: materialize W1b (emb-first K order), Xg, emb_bf --
// blocks 0..1023: W1b rows | 1024..3071: Xg (4 seq rows each) | 3072..3571: emb->bf16
__global__ void build_all(const int* __restrict__ ctx, const float* __restrict__ gz,
                          const float* __restrict__ emb, const float* __restrict__ w1,
                          bf16_t* __restrict__ Xg, bf16_t* __restrict__ W,
                          bf16_t* __restrict__ EB) {
    const int b = blockIdx.x;
    if (b < 1024) {                       // W1b row h, permuted K
        const int h = b;
        for (int g = threadIdx.x; g < DP / 4; g += 256) {
            bf16x4 o;
            if (g < 672) {                // emb region: knew = g*4; c=knew>>7, e=knew&127
                const int knew = g * 4;
                const float4 v = *(const float4*)&w1[(size_t)h * D_RAW + (knew >> 7) * 164 + (knew & 127)];
                o = bf16x4{(bf16_t)v.x, (bf16_t)v.y, (bf16_t)v.z, (bf16_t)v.w};
            } else {                      // gz region: m = g*4-2688 -> c=m/36, j=m%36
                const int m = g * 4 - 2688;
                float t[4];
#pragma unroll
                for (int u = 0; u < 4; ++u) {
                    const int mm = m + u;
                    t[u] = (mm < 756) ? w1[(size_t)h * D_RAW + (mm / 36) * 164 + 128 + (mm % 36)] : 0.f;
                }
                o = bf16x4{(bf16_t)t[0], (bf16_t)t[1], (bf16_t)t[2], (bf16_t)t[3]};
            }
            *(bf16x4*)&W[(size_t)h * DP + g * 4] = o;
        }
    } else if (b < 3072) {                // Xg: packed gz copy + pad (756 -> 768)
        const int s_base = (b - 1024) * 4;
        for (int g = threadIdx.x; g < 4 * 192; g += 256) {
            const int r = g / 192, gg = g - r * 192;
            const int s = s_base + r;
            bf16x4 o = bf16x4{(bf16_t)0.f, (bf16_t)0.f, (bf16_t)0.f, (bf16_t)0.f};
            if (gg < 189) {               // 189*4 = 756 exactly
                const float4 v = *(const float4*)&gz[(size_t)s * 756 + gg * 4];
                o = bf16x4{(bf16_t)v.x, (bf16_t)v.y, (bf16_t)v.z, (bf16_t)v.w};
            }
            *(bf16x4*)&Xg[(size_t)s * GZP + gg * 4] = o;
        }
    } else {                              // emb f32 -> bf16, flat 8000*128
        const size_t base = (size_t)(b - 3072) * 2048;
        for (int g = threadIdx.x; g < 512; g += 256) {
            const float4 v = *(const float4*)&emb[base + g * 4];
            bf16x4 o = bf16x4{(bf16_t)v.x, (bf16_t)v.y, (bf16_t)v.z, (bf16_t)v.w};
            *(bf16x4*)&EB[base + g * 4] = o;
        }
    }
}

// ---------------- Phase 1: h = relu(X @ W1^T + b1); Fp = h @ w2_slice^T ----
// 128x128 tile, BK=64, 256 threads (4 waves, 2x2, 64x64 per wave).
// LDS 69.4 KB -> 2 blocks/CU: the per-tile vmcnt(0)+barrier drain and the
// LDS-read bursts of one block overlap the other block's MFMA (m97's
// mechanism; round-1's ledger showed per-tile cost = 1242 MFMA + 1536
// LDS-read + drain, fully serialized at 1 block/CU). Double-buffered,
// prefetch distance 1, ONE barrier per tile (stage into buf(t+1)=buf(t-1)
// whose reads completed before the end-of-(t-1) barrier; frag ds_reads
// retire before MFMA -> barrier). Verified kg^(row&7) swizzle throughout.
// emb A-tiles (t<42) gather direct from EB via ctx LDS cache (u16, 128x21).
// Fused feats epilogue (round-7 pattern, re-indexed for 128 rows).
__global__ __launch_bounds__(256) void gemm1(const int* __restrict__ ctx,
                                             const bf16_t* __restrict__ EB,
                                             const bf16_t* __restrict__ Xg,
                                             const bf16_t* __restrict__ W,
                                             const float* __restrict__ b1,
                                             const float* __restrict__ w2,
                                             const float* __restrict__ b2,
                                             float* __restrict__ Fp) {
    __shared__ bf16_t As[2][128 * 64];        // 2 x 16 KB
    __shared__ bf16_t Bs[2][128 * 64];        // 2 x 16 KB
    __shared__ unsigned short ctxs[128 * 21]; // 5.375 KB (total 69.4 KB -> 2 blocks/CU)
    const int tid  = threadIdx.x;
    const int wave = tid >> 6, lane = tid & 63;
    const int s0 = blockIdx.x * 128, h0 = blockIdx.y * 128;
    const int wm = (wave >> 1) * 64;     // 2 wave-rows
    const int wn = (wave & 1) * 64;      // 2 wave-cols

    const int arow = tid >> 3;                         // 0..31
    const int akg  = (tid & 7) ^ (arow & 7);           // inverse-swizzled source k-group
    const bf16_t* gB = W + (size_t)(h0 + arow) * DP + akg * 8;

    const int lrow  = lane & 15;
    const int khalf = lane >> 4;         // 0..3
    const int lr7   = lrow & 7;

    // ctx table -> LDS (u16): rows s0..s0+127, flat copy
    for (int j = tid; j < 128 * C_CTX; j += 256)
        ctxs[j] = (unsigned short)ctx[s0 * C_CTX + j];
    asm volatile("s_waitcnt lgkmcnt(0)" ::: "memory");
    __builtin_amdgcn_s_barrier();

    // prologue: stage tile 0 (emb, c=0) into buf 0 — 8 loads
    {
        const int e0 = akg * 8;
#pragma unroll
        for (int i = 0; i < 4; ++i) {
            const int cv = ctxs[(i * 32 + arow) * 21];
            async_copy16(EB + (size_t)cv * 128 + e0, &As[0][(i * 256 + tid) * 8]);
        }
#pragma unroll
        for (int i = 0; i < 4; ++i)
            async_copy16(gB + (size_t)i * 32 * DP, &Bs[0][(i * 256 + tid) * 8]);
    }
    asm volatile("s_waitcnt vmcnt(0)" ::: "memory");
    __builtin_amdgcn_s_barrier();

    f32x4 acc[4][4] = {};
    const int NT = DP / 64;              // 54 (tiles 0..41 emb, 42..53 gz)
    for (int t = 0; t < NT; ++t) {
        const int cur = t & 1, nxt = cur ^ 1;
        const int tt = t + 1;
        const bool st = tt < NT;

        // all register fragments for this K-tile: 8 A + 8 B = 16 ds_read_b128
        bf16x8 a[2][2][2];     // [sp][ks][mt]
        bf16x8 b[2][2][2];     // [qn][ks][nt]
#pragma unroll
        for (int ks = 0; ks < 2; ++ks) {
            const int kgr = ((ks * 4 + khalf) ^ lr7) * 8;
#pragma unroll
            for (int sp = 0; sp < 2; ++sp)
#pragma unroll
                for (int mt = 0; mt < 2; ++mt)
                    a[sp][ks][mt] = *(const bf16x8*)&As[cur][(wm + sp * 32 + mt * 16 + lrow) * 64 + kgr];
#pragma unroll
            for (int qn = 0; qn < 2; ++qn)
#pragma unroll
                for (int nt = 0; nt < 2; ++nt)
                    b[qn][ks][nt] = *(const bf16x8*)&Bs[cur][(wn + qn * 32 + nt * 16 + lrow) * 64 + kgr];
        }
        // stage next tile into the other buffer (its readers finished at t-1)
        if (st) {
            if (tt < 42) {
                const int c_ = tt >> 1;
                const int e0 = (tt & 1) * 64 + akg * 8;
#pragma unroll
                for (int i = 0; i < 4; ++i) {
                    const int cv = ctxs[(i * 32 + arow) * 21 + c_];
                    async_copy16(EB + (size_t)cv * 128 + e0, &As[nxt][(i * 256 + tid) * 8]);
                }
            } else {
                const int m0 = (tt - 42) * 64 + akg * 8;
#pragma unroll
                for (int i = 0; i < 4; ++i)
                    async_copy16(Xg + (size_t)(s0 + i * 32 + arow) * GZP + m0, &As[nxt][(i * 256 + tid) * 8]);
            }
#pragma unroll
            for (int i = 0; i < 4; ++i)
                async_copy16(gB + (size_t)i * 32 * DP + tt * 64, &Bs[nxt][(i * 256 + tid) * 8]);
        }
        __builtin_amdgcn_s_setprio(1);
#pragma unroll
        for (int ks = 0; ks < 2; ++ks)
#pragma unroll
            for (int sp = 0; sp < 2; ++sp)
#pragma unroll
                for (int qn = 0; qn < 2; ++qn)
#pragma unroll
                    for (int mt = 0; mt < 2; ++mt)
#pragma unroll
                        for (int nt = 0; nt < 2; ++nt)
                            acc[sp * 2 + mt][qn * 2 + nt] = __builtin_amdgcn_mfma_f32_16x16x32_bf16(
                                a[sp][ks][mt], b[qn][ks][nt], acc[sp * 2 + mt][qn * 2 + nt], 0, 0, 0);
        __builtin_amdgcn_s_setprio(0);
        if (st) asm volatile("s_waitcnt vmcnt(0)" ::: "memory");
        __builtin_amdgcn_s_barrier();
    }

    // ---- fused feats epilogue ----
    // After the final barrier no wave touches As/Bs: reuse them.
    bf16_t* Hl = &As[0][0];              // 128 x 128 bf16 (32 KB, spans As[0..1])
    bf16_t* Wl = &Bs[0][0];              // 32 x 128 bf16 (8 KB)

    // stage w2 slice: 32 tags x 128 h (f32 -> bf16), 2x8 values/thread
#pragma unroll
    for (int rep = 0; rep < 2; ++rep) {
        const int t8 = tid >> 3;            // 0..31 tag
        const int hl = (tid & 7) * 2 + rep; // 0..15 k-group
        const float* wsrc = w2 + (size_t)t8 * H_DIM + h0 + hl * 8;
        const float4 y0 = *(const float4*)wsrc;
        const float4 y1 = *(const float4*)(wsrc + 4);
        bf16x8 wv = {(bf16_t)y0.x, (bf16_t)y0.y, (bf16_t)y0.z, (bf16_t)y0.w,
                     (bf16_t)y1.x, (bf16_t)y1.y, (bf16_t)y1.z, (bf16_t)y1.w};
        *(bf16x8*)&Wl[(t8 * 16 + (hl ^ (t8 & 7))) * 8] = wv;
    }

    // H tile (relu + bf16) -> LDS, swizzled: Hl[s][ (j/8 ^ s&7)*8 + j%8 ]
    const int crow = (lane >> 4) * 4;
    const int ccol = lane & 15;
#pragma unroll
    for (int nt = 0; nt < 4; ++nt) {
        const int jl = wn + nt * 16 + ccol;          // 0..127 local h
        const float bv = b1[h0 + jl];
#pragma unroll
        for (int mt = 0; mt < 4; ++mt) {
#pragma unroll
            for (int r = 0; r < 4; ++r) {
                const int sl = wm + mt * 16 + crow + r;    // 0..127 local s
                const float v = acc[mt][nt][r] + bv;
                Hl[sl * 128 + ((jl >> 3) ^ (sl & 7)) * 8 + (jl & 7)] = (bf16_t)fmaxf(v, 0.f);
            }
        }
    }
    __syncthreads();

    // mini-GEMM: Fpart[s][t] = H[s][:] . w2[t][:] over this 128-h slice.
    // wave handles 32 s-rows x all 32 tags; K=128 in 4 ks-steps of 32.
    f32x4 acc2[2][2] = {};
    const int wm2 = wave * 32;
#pragma unroll
    for (int ks = 0; ks < 4; ++ks) {
        const int slot = ((ks * 4 + khalf) ^ lr7) * 8;
        bf16x8 ah[2], bw[2];
#pragma unroll
        for (int mt = 0; mt < 2; ++mt)
            ah[mt] = *(const bf16x8*)&Hl[(wm2 + mt * 16 + lrow) * 128 + slot];
#pragma unroll
        for (int nt = 0; nt < 2; ++nt)
            bw[nt] = *(const bf16x8*)&Wl[(nt * 16 + lrow) * 128 + slot];
#pragma unroll
        for (int mt = 0; mt < 2; ++mt)
#pragma unroll
            for (int nt = 0; nt < 2; ++nt)
                acc2[mt][nt] = __builtin_amdgcn_mfma_f32_16x16x32_bf16(ah[mt], bw[nt], acc2[mt][nt], 0, 0, 0);
    }
    const int bj = h0 >> 7;
#pragma unroll
    for (int nt = 0; nt < 2; ++nt) {
        const int tcol = nt * 16 + ccol;
        const float badd = (bj == 7) ? b2[tcol] : 0.f;
#pragma unroll
        for (int mt = 0; mt < 2; ++mt) {
#pragma unroll
            for (int r = 0; r < 4; ++r) {
                const int sr = s0 + wm2 + mt * 16 + crow + r;
                Fp[((size_t)bj * S_LEN + sr) * T_TAG + tcol] = acc2[mt][nt][r] + badd;
            }
        }
    }
}

// ---------------- CRF pass A: per-chunk matrix-chain products --------------
// ONE chain per 64-lane wave: lane (h=lane>>5, n=lane&31) computes the
// half-dot over k in [h*16, h*16+16), one shfl_xor(32) merges halves.
// 2048 waves = 2 waves/SIMD hide the per-step LDS round-trip.
__global__ __launch_bounds__(512) void crfA(const float* __restrict__ Fp,
                                            const float* __restrict__ trans,
                                            float* __restrict__ QT,
                                            float* __restrict__ sigma,
                                            float* __restrict__ Fsum) {
    __shared__ float fl[L_CHUNK * 32];
    __shared__ float vb[8][64];
    const int c    = blockIdx.x >> 2;
    const int tid  = threadIdx.x;
    const int wave = tid >> 6;
    const int lane = tid & 63;
    const int n    = lane & 31;
    const int h    = lane >> 5;                 // half: k in [h*16, h*16+16)
    const int p    = ((blockIdx.x & 3) << 3) + wave;
    const int s0   = c * L_CHUNK;
    for (int i = tid; i < L_CHUNK * 32; i += 512) {
        const size_t idx = (size_t)s0 * 32 + i;
        float accf = 0.f;
#pragma unroll
        for (int j = 0; j < 8; ++j) accf += Fp[(size_t)j * S_LEN * T_TAG + idx];
        fl[i] = accf;
        Fsum[idx] = accf;
    }
    __syncthreads();

    float etl[16];
#pragma unroll
    for (int j = 0; j < 16; ++j) etl[j] = __expf(trans[n * 32 + h * 16 + j]);

    float* vrow = &vb[wave][0];
    float v  = __expf(trans[n * 32 + p] + fl[n]);   // identical in both halves
    float sg = 0.f;
    for (int s = 1; s < L_CHUNK; ++s) {
        vrow[lane] = v;                             // vrow[k] = v[k] (dup at 32+k)
        __builtin_amdgcn_s_waitcnt(0xC07F);         // lgkmcnt(0): wave-coherent LDS
        float a0 = 0.f, a1 = 0.f, a2 = 0.f, a3 = 0.f;
#pragma unroll
        for (int q = 0; q < 4; ++q) {
            const float4 wv = *(const float4*)&vrow[h * 16 + q * 4];
            a0 = __builtin_fmaf(etl[q * 4 + 0], wv.x, a0);
            a1 = __builtin_fmaf(etl[q * 4 + 1], wv.y, a1);
            a2 = __builtin_fmaf(etl[q * 4 + 2], wv.z, a2);
            a3 = __builtin_fmaf(etl[q * 4 + 3], wv.w, a3);
        }
        float part = (a0 + a1) + (a2 + a3);
        part += __shfl_xor(part, 32);               // merge halves: full dot in all lanes
        v = __expf(fl[s * 32 + n]) * part;
        if ((s & 7) == 7) {
            float m = v;
#pragma unroll
            for (int off = 16; off; off >>= 1) m = fmaxf(m, __shfl_xor(m, off, 32));
            if (m > 0.f) { v *= 1.0f / m; sg += __logf(m); }
        }
    }
    if (h == 0) {
        QT[(c * 32 + p) * 32 + n] = v;
        if (n == 0) sigma[c * 32 + p] = sg;
    }
}

// ---------------- CRF pass B: parallel matrix fold ----------------
__global__ __launch_bounds__(1024) void crf_fold(const float* __restrict__ Qin,
                                                 const float* __restrict__ Sin,
                                                 const int fold, const int final,
                                                 float* __restrict__ Qout,
                                                 float* __restrict__ Sout,
                                                 const float* __restrict__ trans,
                                                 const float* __restrict__ F,
                                                 const int* __restrict__ lab,
                                                 float* __restrict__ out) {
    __shared__ float A[32][33];
    __shared__ float M[32][33];
    __shared__ float sgf[32];
    __shared__ float gred[16];
    __shared__ float gold_s;

    const int t = threadIdx.x;
    const int p = t >> 5, n = t & 31;
    const int c0 = blockIdx.x * fold;

    if (final) {
        float ga = 0.f;
        for (int s = t; s < S_LEN; s += 1024) {
            const int tg = lab[s];
            ga += F[(size_t)s * T_TAG + tg];
            const int tp = (s == 0) ? START_TAG : lab[s - 1];
            ga += trans[tg * T_TAG + tp];
        }
        if (t == 0) ga += trans[STOP_TAG * T_TAG + lab[S_LEN - 1]];
#pragma unroll
        for (int off = 32; off; off >>= 1) ga += __shfl_down(ga, off, 64);
        if ((t & 63) == 0) gred[t >> 6] = ga;
    }

    A[n][p] = Qin[(size_t)(c0 * 32 + p) * 32 + n];
    float sA = Sin[c0 * 32 + p];
    float mreg = Qin[(size_t)((c0 + 1) * 32 + p) * 32 + n];

    for (int i = 1; i < fold; ++i) {
        const float sMn = Sin[(c0 + i) * 32 + n];
        float mmax = sMn;
#pragma unroll
        for (int off = 16; off; off >>= 1) mmax = fmaxf(mmax, __shfl_xor(mmax, off, 32));
        const float sMp = Sin[(c0 + i) * 32 + p];
        __syncthreads();
        M[n][p] = mreg * __expf(sMp - mmax);
        if (i + 1 < fold) mreg = Qin[(size_t)((c0 + i + 1) * 32 + p) * 32 + n];
        __syncthreads();
        float acc = 0.f;
#pragma unroll 8
        for (int k = 0; k < 32; ++k)
            acc += M[n][k] * A[k][p];
        float cm = acc;
#pragma unroll
        for (int off = 16; off; off >>= 1) cm = fmaxf(cm, __shfl_xor(cm, off, 32));
        cm = fmaxf(cm, 1e-37f);
        __syncthreads();
        A[n][p] = acc / cm;
        sA = sA + mmax + __logf(cm);
    }
    __syncthreads();

    if (!final) {
        Qout[(size_t)(blockIdx.x * 32 + p) * 32 + n] = A[n][p];
        if (n == 0) Sout[blockIdx.x * 32 + p] = sA;
        return;
    }

    if (n == 0) sgf[p] = sA;
    if (t == 0) {
        float s = 0.f;
#pragma unroll
        for (int i = 0; i < 16; ++i) s += gred[i];
        gold_s = s;
    }
    __syncthreads();
    if (t < 32) {
        float v = A[t][START_TAG] * __expf(trans[STOP_TAG * T_TAG + t]);
#pragma unroll
        for (int off = 16; off; off >>= 1) v += __shfl_xor(v, off, 32);
        if (t == 0) out[0] = sgf[START_TAG] + __logf(v) - gold_s;
    }
}

// ---------------- launch ----------------
extern "C" void kernel_launch(void* const* d_in, const int* in_sizes, int n_in,
                              void* d_out, int out_size, void* d_ws, size_t ws_size,
                              hipStream_t stream) {
    const int*   ctx   = (const int*)d_in[0];
    const float* gz    = (const float*)d_in[1];
    const int*   lab   = (const int*)d_in[2];
    const float* emb   = (const float*)d_in[3];
    const float* w1    = (const float*)d_in[4];
    const float* b1    = (const float*)d_in[5];
    const float* w2    = (const float*)d_in[6];
    const float* b2    = (const float*)d_in[7];
    const float* trans = (const float*)d_in[8];
    float* out = (float*)d_out;

    char* ws = (char*)d_ws;
    bf16_t* W1b = (bf16_t*)(ws + 0);               // 1024*3456*2 =  7,077,888
    bf16_t* EB  = (bf16_t*)(ws + 7077888);         // 8000*128*2  =  2,048,000
    bf16_t* Xg  = (bf16_t*)(ws + 9126400);         // 8192*768*2  = 12,582,912
    float*  Fp  = (float*)(ws + 21709312);         // 8*8192*32*4 =  8,388,608
    float*  F   = (float*)(ws + 30097920);         // 8192*32*4   =  1,048,576
    float*  QT  = (float*)(ws + 31146496);         // 64*32*32*4  =    262,144
    float*  sg  = (float*)(ws + 31408640);         // 64*32*4     =      8,192
    float*  Q1  = (float*)(ws + 31416832);         // 8*32*32*4   =     32,768
    float*  S1  = (float*)(ws + 31449600);         // 8*32*4      =      1,024

    build_all<<<3572, 256, 0, stream>>>(ctx, gz, emb, w1, Xg, W1b, EB);
    gemm1<<<dim3(S_LEN / 128, H_DIM / 128), 256, 0, stream>>>(ctx, EB, Xg, W1b, b1, w2, b2, Fp);
    crfA<<<K_CHUNKS * 4, 512, 0, stream>>>(Fp, trans, QT, sg, F);
    crf_fold<<<8, 1024, 0, stream>>>(QT, sg, 8, 0, Q1, S1, trans, F, lab, out);
    crf_fold<<<1, 1024, 0, stream>>>(Q1, S1, 8, 1, nullptr, nullptr, trans, F, lab, out);
}

// Round 10
// 228.225 us; speedup vs baseline: 1.2810x; 1.0083x over previous
//
#include <hip/hip_runtime.h>

#define S_LEN 8192
#define C_CTX 21
#define E_DIM 128
#define G_DIM 36
#define H_DIM 1024
#define T_TAG 32
#define D_RAW 3444          // 21*(128+36)
#define DP 3456             // emb-first K layout: 21*128=2688 emb | 756 gz | 12 pad
#define GZP 768             // padded gz width
#define START_TAG 30
#define STOP_TAG 31
#define NEGV -10000.0f
#define K_CHUNKS 64
#define L_CHUNK 128         // K_CHUNKS * L_CHUNK == S_LEN

typedef __bf16 bf16_t;
typedef __bf16 bf16x4 __attribute__((ext_vector_type(4)));
typedef __bf16 bf16x8 __attribute__((ext_vector_type(8)));
typedef float  f32x4  __attribute__((ext_vector_type(4)));

__device__ inline void async_copy16(const bf16_t* g, bf16_t* l) {
    __builtin_amdgcn_global_load_lds(
        (const __attribute__((address_space(1))) void*)g,
        (__attribute__((address_space(3))) void*)l, 16, 0, 0);
}

// ---------------- Phase 0: materialize W1b (emb-first K order), Xg, emb_bf --
// blocks 0..1023: W1b rows | 1024..3071: Xg (4 seq rows each) | 3072..3571: emb->bf16
__global__ void build_all(const int* __restrict__ ctx, const float* __restrict__ gz,
                          const float* __restrict__ emb, const float* __restrict__ w1,
                          bf16_t* __restrict__ Xg, bf16_t* __restrict__ W,
                          bf16_t* __restrict__ EB) {
    const int b = blockIdx.x;
    if (b < 1024) {                       // W1b row h, permuted K
        const int h = b;
        for (int g = threadIdx.x; g < DP / 4; g += 256) {
            bf16x4 o;
            if (g < 672) {                // emb region: knew = g*4; c=knew>>7, e=knew&127
                const int knew = g * 4;
                const float4 v = *(const float4*)&w1[(size_t)h * D_RAW + (knew >> 7) * 164 + (knew & 127)];
                o = bf16x4{(bf16_t)v.x, (bf16_t)v.y, (bf16_t)v.z, (bf16_t)v.w};
            } else {                      // gz region: m = g*4-2688 -> c=m/36, j=m%36
                const int m = g * 4 - 2688;
                float t[4];
#pragma unroll
                for (int u = 0; u < 4; ++u) {
                    const int mm = m + u;
                    t[u] = (mm < 756) ? w1[(size_t)h * D_RAW + (mm / 36) * 164 + 128 + (mm % 36)] : 0.f;
                }
                o = bf16x4{(bf16_t)t[0], (bf16_t)t[1], (bf16_t)t[2], (bf16_t)t[3]};
            }
            *(bf16x4*)&W[(size_t)h * DP + g * 4] = o;
        }
    } else if (b < 3072) {                // Xg: packed gz copy + pad (756 -> 768)
        const int s_base = (b - 1024) * 4;
        for (int g = threadIdx.x; g < 4 * 192; g += 256) {
            const int r = g / 192, gg = g - r * 192;
            const int s = s_base + r;
            bf16x4 o = bf16x4{(bf16_t)0.f, (bf16_t)0.f, (bf16_t)0.f, (bf16_t)0.f};
            if (gg < 189) {               // 189*4 = 756 exactly
                const float4 v = *(const float4*)&gz[(size_t)s * 756 + gg * 4];
                o = bf16x4{(bf16_t)v.x, (bf16_t)v.y, (bf16_t)v.z, (bf16_t)v.w};
            }
            *(bf16x4*)&Xg[(size_t)s * GZP + gg * 4] = o;
        }
    } else {                              // emb f32 -> bf16, flat 8000*128
        const size_t base = (size_t)(b - 3072) * 2048;
        for (int g = threadIdx.x; g < 512; g += 256) {
            const float4 v = *(const float4*)&emb[base + g * 4];
            bf16x4 o = bf16x4{(bf16_t)v.x, (bf16_t)v.y, (bf16_t)v.z, (bf16_t)v.w};
            *(bf16x4*)&EB[base + g * 4] = o;
        }
    }
}

// ---------------- Phase 1: h = relu(X @ W1^T + b1); Fp = h @ w2_slice^T ----
// 128x128 tile, BK=64, 256 threads (4 waves, 2x2, 64x64 per wave), 2 blocks/CU.
// Double-buffered, prefetch distance 1, ONE barrier per tile. Stage-issue is
// placed BEFORE the frag ds_reads: widens the issue->vmcnt(0) gap by ~190 cyc
// so the (L2-resident) staging loads land under the ds_read burst + MFMA.
// Verified kg^(row&7) swizzle; emb A-tiles gather direct from EB via ctx LDS
// cache; fused feats epilogue.
__global__ __launch_bounds__(256) void gemm1(const int* __restrict__ ctx,
                                             const bf16_t* __restrict__ EB,
                                             const bf16_t* __restrict__ Xg,
                                             const bf16_t* __restrict__ W,
                                             const float* __restrict__ b1,
                                             const float* __restrict__ w2,
                                             const float* __restrict__ b2,
                                             float* __restrict__ Fp) {
    __shared__ bf16_t As[2][128 * 64];        // 2 x 16 KB
    __shared__ bf16_t Bs[2][128 * 64];        // 2 x 16 KB
    __shared__ unsigned short ctxs[128 * 21]; // 5.375 KB (total 69.4 KB -> 2 blocks/CU)
    const int tid  = threadIdx.x;
    const int wave = tid >> 6, lane = tid & 63;
    const int s0 = blockIdx.x * 128, h0 = blockIdx.y * 128;
    const int wm = (wave >> 1) * 64;     // 2 wave-rows
    const int wn = (wave & 1) * 64;      // 2 wave-cols

    const int arow = tid >> 3;                         // 0..31
    const int akg  = (tid & 7) ^ (arow & 7);           // inverse-swizzled source k-group
    const bf16_t* gB = W + (size_t)(h0 + arow) * DP + akg * 8;

    const int lrow  = lane & 15;
    const int khalf = lane >> 4;         // 0..3
    const int lr7   = lrow & 7;

    // ctx table -> LDS (u16): rows s0..s0+127, flat copy
    for (int j = tid; j < 128 * C_CTX; j += 256)
        ctxs[j] = (unsigned short)ctx[s0 * C_CTX + j];
    asm volatile("s_waitcnt lgkmcnt(0)" ::: "memory");
    __builtin_amdgcn_s_barrier();

    // prologue: stage tile 0 (emb, c=0) into buf 0 — 8 loads
    {
        const int e0 = akg * 8;
#pragma unroll
        for (int i = 0; i < 4; ++i) {
            const int cv = ctxs[(i * 32 + arow) * 21];
            async_copy16(EB + (size_t)cv * 128 + e0, &As[0][(i * 256 + tid) * 8]);
        }
#pragma unroll
        for (int i = 0; i < 4; ++i)
            async_copy16(gB + (size_t)i * 32 * DP, &Bs[0][(i * 256 + tid) * 8]);
    }
    asm volatile("s_waitcnt vmcnt(0)" ::: "memory");
    __builtin_amdgcn_s_barrier();

    f32x4 acc[4][4] = {};
    const int NT = DP / 64;              // 54 (tiles 0..41 emb, 42..53 gz)
    for (int t = 0; t < NT; ++t) {
        const int cur = t & 1, nxt = cur ^ 1;
        const int tt = t + 1;
        const bool st = tt < NT;

        // stage next tile FIRST (into the other buffer, freed at t-1's barrier);
        // issue-early so the L2 loads land under the ds_read burst + MFMA.
        if (st) {
            if (tt < 42) {
                const int c_ = tt >> 1;
                const int e0 = (tt & 1) * 64 + akg * 8;
#pragma unroll
                for (int i = 0; i < 4; ++i) {
                    const int cv = ctxs[(i * 32 + arow) * 21 + c_];
                    async_copy16(EB + (size_t)cv * 128 + e0, &As[nxt][(i * 256 + tid) * 8]);
                }
            } else {
                const int m0 = (tt - 42) * 64 + akg * 8;
#pragma unroll
                for (int i = 0; i < 4; ++i)
                    async_copy16(Xg + (size_t)(s0 + i * 32 + arow) * GZP + m0, &As[nxt][(i * 256 + tid) * 8]);
            }
#pragma unroll
            for (int i = 0; i < 4; ++i)
                async_copy16(gB + (size_t)i * 32 * DP + tt * 64, &Bs[nxt][(i * 256 + tid) * 8]);
        }

        // all register fragments for this K-tile: 8 A + 8 B = 16 ds_read_b128
        bf16x8 a[2][2][2];     // [sp][ks][mt]
        bf16x8 b[2][2][2];     // [qn][ks][nt]
#pragma unroll
        for (int ks = 0; ks < 2; ++ks) {
            const int kgr = ((ks * 4 + khalf) ^ lr7) * 8;
#pragma unroll
            for (int sp = 0; sp < 2; ++sp)
#pragma unroll
                for (int mt = 0; mt < 2; ++mt)
                    a[sp][ks][mt] = *(const bf16x8*)&As[cur][(wm + sp * 32 + mt * 16 + lrow) * 64 + kgr];
#pragma unroll
            for (int qn = 0; qn < 2; ++qn)
#pragma unroll
                for (int nt = 0; nt < 2; ++nt)
                    b[qn][ks][nt] = *(const bf16x8*)&Bs[cur][(wn + qn * 32 + nt * 16 + lrow) * 64 + kgr];
        }
        __builtin_amdgcn_s_setprio(1);
#pragma unroll
        for (int ks = 0; ks < 2; ++ks)
#pragma unroll
            for (int sp = 0; sp < 2; ++sp)
#pragma unroll
                for (int qn = 0; qn < 2; ++qn)
#pragma unroll
                    for (int mt = 0; mt < 2; ++mt)
#pragma unroll
                        for (int nt = 0; nt < 2; ++nt)
                            acc[sp * 2 + mt][qn * 2 + nt] = __builtin_amdgcn_mfma_f32_16x16x32_bf16(
                                a[sp][ks][mt], b[qn][ks][nt], acc[sp * 2 + mt][qn * 2 + nt], 0, 0, 0);
        __builtin_amdgcn_s_setprio(0);
        if (st) asm volatile("s_waitcnt vmcnt(0)" ::: "memory");
        __builtin_amdgcn_s_barrier();
    }

    // ---- fused feats epilogue ----
    bf16_t* Hl = &As[0][0];              // 128 x 128 bf16 (32 KB, spans As[0..1])
    bf16_t* Wl = &Bs[0][0];              // 32 x 128 bf16 (8 KB)

#pragma unroll
    for (int rep = 0; rep < 2; ++rep) {
        const int t8 = tid >> 3;            // 0..31 tag
        const int hl = (tid & 7) * 2 + rep; // 0..15 k-group
        const float* wsrc = w2 + (size_t)t8 * H_DIM + h0 + hl * 8;
        const float4 y0 = *(const float4*)wsrc;
        const float4 y1 = *(const float4*)(wsrc + 4);
        bf16x8 wv = {(bf16_t)y0.x, (bf16_t)y0.y, (bf16_t)y0.z, (bf16_t)y0.w,
                     (bf16_t)y1.x, (bf16_t)y1.y, (bf16_t)y1.z, (bf16_t)y1.w};
        *(bf16x8*)&Wl[(t8 * 16 + (hl ^ (t8 & 7))) * 8] = wv;
    }

    const int crow = (lane >> 4) * 4;
    const int ccol = lane & 15;
#pragma unroll
    for (int nt = 0; nt < 4; ++nt) {
        const int jl = wn + nt * 16 + ccol;          // 0..127 local h
        const float bv = b1[h0 + jl];
#pragma unroll
        for (int mt = 0; mt < 4; ++mt) {
#pragma unroll
            for (int r = 0; r < 4; ++r) {
                const int sl = wm + mt * 16 + crow + r;    // 0..127 local s
                const float v = acc[mt][nt][r] + bv;
                Hl[sl * 128 + ((jl >> 3) ^ (sl & 7)) * 8 + (jl & 7)] = (bf16_t)fmaxf(v, 0.f);
            }
        }
    }
    __syncthreads();

    f32x4 acc2[2][2] = {};
    const int wm2 = wave * 32;
#pragma unroll
    for (int ks = 0; ks < 4; ++ks) {
        const int slot = ((ks * 4 + khalf) ^ lr7) * 8;
        bf16x8 ah[2], bw[2];
#pragma unroll
        for (int mt = 0; mt < 2; ++mt)
            ah[mt] = *(const bf16x8*)&Hl[(wm2 + mt * 16 + lrow) * 128 + slot];
#pragma unroll
        for (int nt = 0; nt < 2; ++nt)
            bw[nt] = *(const bf16x8*)&Wl[(nt * 16 + lrow) * 128 + slot];
#pragma unroll
        for (int mt = 0; mt < 2; ++mt)
#pragma unroll
            for (int nt = 0; nt < 2; ++nt)
                acc2[mt][nt] = __builtin_amdgcn_mfma_f32_16x16x32_bf16(ah[mt], bw[nt], acc2[mt][nt], 0, 0, 0);
    }
    const int bj = h0 >> 7;
#pragma unroll
    for (int nt = 0; nt < 2; ++nt) {
        const int tcol = nt * 16 + ccol;
        const float badd = (bj == 7) ? b2[tcol] : 0.f;
#pragma unroll
        for (int mt = 0; mt < 2; ++mt) {
#pragma unroll
            for (int r = 0; r < 4; ++r) {
                const int sr = s0 + wm2 + mt * 16 + crow + r;
                Fp[((size_t)bj * S_LEN + sr) * T_TAG + tcol] = acc2[mt][nt][r] + badd;
            }
        }
    }
}

// ---------------- CRF pass A: per-chunk matrix-chain products + gold partial
// ONE chain per 64-lane wave; 2048 waves = 2 waves/SIMD. fl (the chunk's F
// rows, already in LDS for the chain) additionally feeds a per-chunk gold
// partial: gold_part[c] = sum_s F[s][lab[s]] + trans[lab[s]][lab[s-1]],
// computed by the (blockIdx&3)==0 duplicate. Replaces the final fold's
// strided gold pass and the Fsum buffer entirely.
__global__ __launch_bounds__(512) void crfA(const float* __restrict__ Fp,
                                            const float* __restrict__ trans,
                                            float* __restrict__ QT,
                                            float* __restrict__ sigma,
                                            const int* __restrict__ lab,
                                            float* __restrict__ gold_part) {
    __shared__ float fl[L_CHUNK * 32];
    __shared__ float vb[8][64];
    __shared__ float wred[8];
    const int c    = blockIdx.x >> 2;
    const int tid  = threadIdx.x;
    const int wave = tid >> 6;
    const int lane = tid & 63;
    const int n    = lane & 31;
    const int h    = lane >> 5;                 // half: k in [h*16, h*16+16)
    const int p    = ((blockIdx.x & 3) << 3) + wave;
    const int s0   = c * L_CHUNK;
    for (int i = tid; i < L_CHUNK * 32; i += 512) {
        const size_t idx = (size_t)s0 * 32 + i;
        float accf = 0.f;
#pragma unroll
        for (int j = 0; j < 8; ++j) accf += Fp[(size_t)j * S_LEN * T_TAG + idx];
        fl[i] = accf;
    }
    __syncthreads();

    // gold partial (one duplicate block per chunk)
    const bool goldblk = (blockIdx.x & 3) == 0;
    float gterm = 0.f;
    if (goldblk && tid < L_CHUNK) {
        const int s  = s0 + tid;
        const int tg = lab[s];
        const int tp = (s == 0) ? START_TAG : lab[s - 1];
        gterm = fl[tid * 32 + tg] + trans[tg * T_TAG + tp];
    }
#pragma unroll
    for (int off = 32; off; off >>= 1) gterm += __shfl_down(gterm, off, 64);
    if (goldblk && lane == 0) wred[wave] = gterm;
    __syncthreads();
    if (goldblk && tid == 0) {
        float gsum = 0.f;
#pragma unroll
        for (int i = 0; i < 8; ++i) gsum += wred[i];   // waves 2..7 contributed 0
        gold_part[c] = gsum;
    }

    float etl[16];
#pragma unroll
    for (int j = 0; j < 16; ++j) etl[j] = __expf(trans[n * 32 + h * 16 + j]);

    float* vrow = &vb[wave][0];
    float v  = __expf(trans[n * 32 + p] + fl[n]);   // identical in both halves
    float sg = 0.f;
    for (int s = 1; s < L_CHUNK; ++s) {
        vrow[lane] = v;                             // vrow[k] = v[k] (dup at 32+k)
        __builtin_amdgcn_s_waitcnt(0xC07F);         // lgkmcnt(0): wave-coherent LDS
        float a0 = 0.f, a1 = 0.f, a2 = 0.f, a3 = 0.f;
#pragma unroll
        for (int q = 0; q < 4; ++q) {
            const float4 wv = *(const float4*)&vrow[h * 16 + q * 4];
            a0 = __builtin_fmaf(etl[q * 4 + 0], wv.x, a0);
            a1 = __builtin_fmaf(etl[q * 4 + 1], wv.y, a1);
            a2 = __builtin_fmaf(etl[q * 4 + 2], wv.z, a2);
            a3 = __builtin_fmaf(etl[q * 4 + 3], wv.w, a3);
        }
        float part = (a0 + a1) + (a2 + a3);
        part += __shfl_xor(part, 32);               // merge halves: full dot in all lanes
        v = __expf(fl[s * 32 + n]) * part;
        if ((s & 7) == 7) {
            float m = v;
#pragma unroll
            for (int off = 16; off; off >>= 1) m = fmaxf(m, __shfl_xor(m, off, 32));
            if (m > 0.f) { v *= 1.0f / m; sg += __logf(m); }
        }
    }
    if (h == 0) {
        QT[(c * 32 + p) * 32 + n] = v;
        if (n == 0) sigma[c * 32 + p] = sg;
    }
}

// ---------------- CRF pass B: parallel matrix fold ----------------
__global__ __launch_bounds__(1024) void crf_fold(const float* __restrict__ Qin,
                                                 const float* __restrict__ Sin,
                                                 const int fold, const int final,
                                                 float* __restrict__ Qout,
                                                 float* __restrict__ Sout,
                                                 const float* __restrict__ trans,
                                                 const float* __restrict__ gold_part,
                                                 const int* __restrict__ lab,
                                                 float* __restrict__ out) {
    __shared__ float A[32][33];
    __shared__ float M[32][33];
    __shared__ float sgf[32];
    __shared__ float gold_s;

    const int t = threadIdx.x;
    const int p = t >> 5, n = t & 31;
    const int c0 = blockIdx.x * fold;

    if (final && t == 0) {
        float s = 0.f;
#pragma unroll
        for (int i = 0; i < K_CHUNKS; ++i) s += gold_part[i];
        gold_s = s + trans[STOP_TAG * T_TAG + lab[S_LEN - 1]];
    }

    A[n][p] = Qin[(size_t)(c0 * 32 + p) * 32 + n];
    float sA = Sin[c0 * 32 + p];
    float mreg = Qin[(size_t)((c0 + 1) * 32 + p) * 32 + n];

    for (int i = 1; i < fold; ++i) {
        const float sMn = Sin[(c0 + i) * 32 + n];
        float mmax = sMn;
#pragma unroll
        for (int off = 16; off; off >>= 1) mmax = fmaxf(mmax, __shfl_xor(mmax, off, 32));
        const float sMp = Sin[(c0 + i) * 32 + p];
        __syncthreads();
        M[n][p] = mreg * __expf(sMp - mmax);
        if (i + 1 < fold) mreg = Qin[(size_t)((c0 + i + 1) * 32 + p) * 32 + n];
        __syncthreads();
        float acc = 0.f;
#pragma unroll 8
        for (int k = 0; k < 32; ++k)
            acc += M[n][k] * A[k][p];
        float cm = acc;
#pragma unroll
        for (int off = 16; off; off >>= 1) cm = fmaxf(cm, __shfl_xor(cm, off, 32));
        cm = fmaxf(cm, 1e-37f);
        __syncthreads();
        A[n][p] = acc / cm;
        sA = sA + mmax + __logf(cm);
    }
    __syncthreads();

    if (!final) {
        Qout[(size_t)(blockIdx.x * 32 + p) * 32 + n] = A[n][p];
        if (n == 0) Sout[blockIdx.x * 32 + p] = sA;
        return;
    }

    if (n == 0) sgf[p] = sA;
    __syncthreads();
    if (t < 32) {
        float v = A[t][START_TAG] * __expf(trans[STOP_TAG * T_TAG + t]);
#pragma unroll
        for (int off = 16; off; off >>= 1) v += __shfl_xor(v, off, 32);
        if (t == 0) out[0] = sgf[START_TAG] + __logf(v) - gold_s;
    }
}

// ---------------- launch ----------------
extern "C" void kernel_launch(void* const* d_in, const int* in_sizes, int n_in,
                              void* d_out, int out_size, void* d_ws, size_t ws_size,
                              hipStream_t stream) {
    const int*   ctx   = (const int*)d_in[0];
    const float* gz    = (const float*)d_in[1];
    const int*   lab   = (const int*)d_in[2];
    const float* emb   = (const float*)d_in[3];
    const float* w1    = (const float*)d_in[4];
    const float* b1    = (const float*)d_in[5];
    const float* w2    = (const float*)d_in[6];
    const float* b2    = (const float*)d_in[7];
    const float* trans = (const float*)d_in[8];
    float* out = (float*)d_out;

    char* ws = (char*)d_ws;
    bf16_t* W1b = (bf16_t*)(ws + 0);               // 1024*3456*2 =  7,077,888
    bf16_t* EB  = (bf16_t*)(ws + 7077888);         // 8000*128*2  =  2,048,000
    bf16_t* Xg  = (bf16_t*)(ws + 9126400);         // 8192*768*2  = 12,582,912
    float*  Fp  = (float*)(ws + 21709312);         // 8*8192*32*4 =  8,388,608
    float*  goldp = (float*)(ws + 30097920);       // 64*4        =        256
    float*  QT  = (float*)(ws + 31146496);         // 64*32*32*4  =    262,144
    float*  sg  = (float*)(ws + 31408640);         // 64*32*4     =      8,192
    float*  Q1  = (float*)(ws + 31416832);         // 8*32*32*4   =     32,768
    float*  S1  = (float*)(ws + 31449600);         // 8*32*4      =      1,024

    build_all<<<3572, 256, 0, stream>>>(ctx, gz, emb, w1, Xg, W1b, EB);
    gemm1<<<dim3(S_LEN / 128, H_DIM / 128), 256, 0, stream>>>(ctx, EB, Xg, W1b, b1, w2, b2, Fp);
    crfA<<<K_CHUNKS * 4, 512, 0, stream>>>(Fp, trans, QT, sg, lab, goldp);
    crf_fold<<<8, 1024, 0, stream>>>(QT, sg, 8, 0, Q1, S1, trans, nullptr, nullptr, nullptr);
    crf_fold<<<1, 1024, 0, stream>>>(Q1, S1, 8, 1, nullptr, nullptr, trans, goldp, lab, out);
}

// Round 12
// 217.803 us; speedup vs baseline: 1.3423x; 1.0478x over previous
//
#include <hip/hip_runtime.h>

#define S_LEN 8192
#define C_CTX 21
#define E_DIM 128
#define G_DIM 36
#define H_DIM 1024
#define T_TAG 32
#define D_RAW 3444          // 21*(128+36)
#define DP 3456             // emb-first K layout: 21*128=2688 emb | 756 gz | 12 pad
#define GZP 768             // padded gz width
#define START_TAG 30
#define STOP_TAG 31
#define NEGV -10000.0f
#define K_CHUNKS 64
#define L_CHUNK 128         // K_CHUNKS * L_CHUNK == S_LEN

typedef __bf16 bf16_t;
typedef __bf16 bf16x4 __attribute__((ext_vector_type(4)));
typedef __bf16 bf16x8 __attribute__((ext_vector_type(8)));
typedef float  f32x4  __attribute__((ext_vector_type(4)));

__device__ inline void async_copy16(const bf16_t* g, bf16_t* l) {
    __builtin_amdgcn_global_load_lds(
        (const __attribute__((address_space(1))) void*)g,
        (__attribute__((address_space(3))) void*)l, 16, 0, 0);
}

// ---------------- Phase 0: materialize W1b (emb-first K order), Xg, emb_bf --
// blocks 0..1023: W1b rows | 1024..3071: Xg (4 seq rows each) | 3072..3571: emb->bf16
__global__ void build_all(const int* __restrict__ ctx, const float* __restrict__ gz,
                          const float* __restrict__ emb, const float* __restrict__ w1,
                          bf16_t* __restrict__ Xg, bf16_t* __restrict__ W,
                          bf16_t* __restrict__ EB) {
    const int b = blockIdx.x;
    if (b < 1024) {                       // W1b row h, permuted K
        const int h = b;
        for (int g = threadIdx.x; g < DP / 4; g += 256) {
            bf16x4 o;
            if (g < 672) {                // emb region: knew = g*4; c=knew>>7, e=knew&127
                const int knew = g * 4;
                const float4 v = *(const float4*)&w1[(size_t)h * D_RAW + (knew >> 7) * 164 + (knew & 127)];
                o = bf16x4{(bf16_t)v.x, (bf16_t)v.y, (bf16_t)v.z, (bf16_t)v.w};
            } else {                      // gz region: m = g*4-2688 -> c=m/36, j=m%36
                const int m = g * 4 - 2688;
                float t[4];
#pragma unroll
                for (int u = 0; u < 4; ++u) {
                    const int mm = m + u;
                    t[u] = (mm < 756) ? w1[(size_t)h * D_RAW + (mm / 36) * 164 + 128 + (mm % 36)] : 0.f;
                }
                o = bf16x4{(bf16_t)t[0], (bf16_t)t[1], (bf16_t)t[2], (bf16_t)t[3]};
            }
            *(bf16x4*)&W[(size_t)h * DP + g * 4] = o;
        }
    } else if (b < 3072) {                // Xg: packed gz copy + pad (756 -> 768)
        const int s_base = (b - 1024) * 4;
        for (int g = threadIdx.x; g < 4 * 192; g += 256) {
            const int r = g / 192, gg = g - r * 192;
            const int s = s_base + r;
            bf16x4 o = bf16x4{(bf16_t)0.f, (bf16_t)0.f, (bf16_t)0.f, (bf16_t)0.f};
            if (gg < 189) {               // 189*4 = 756 exactly
                const float4 v = *(const float4*)&gz[(size_t)s * 756 + gg * 4];
                o = bf16x4{(bf16_t)v.x, (bf16_t)v.y, (bf16_t)v.z, (bf16_t)v.w};
            }
            *(bf16x4*)&Xg[(size_t)s * GZP + gg * 4] = o;
        }
    } else {                              // emb f32 -> bf16, flat 8000*128
        const size_t base = (size_t)(b - 3072) * 2048;
        for (int g = threadIdx.x; g < 512; g += 256) {
            const float4 v = *(const float4*)&emb[base + g * 4];
            bf16x4 o = bf16x4{(bf16_t)v.x, (bf16_t)v.y, (bf16_t)v.z, (bf16_t)v.w};
            *(bf16x4*)&EB[base + g * 4] = o;
        }
    }
}

// ---------------- Phase 1: h = relu(X @ W1^T + b1); Fp = h @ w2_slice^T ----
// 128x128 tile, BK=64, 256 threads (4 waves, 2x2, 64x64 per wave), 2 blocks/CU.
// Double-buffered, prefetch distance 1, ONE barrier per tile. Loop order is
// the round-9 verified one (60.2 µs, MfmaUtil 40): frag ds_reads FIRST, then
// stage issues, then MFMA — stages issue in the MFMA shadow. (Round-10's
// stage-first order regressed to 72 µs: it delayed the fragment reads on the
// MFMA critical path and collided gload_lds writebacks with the ds_read
// burst.) Verified kg^(row&7) swizzle; emb A-tiles gather direct from EB via
// ctx LDS cache; fused feats epilogue.
__global__ __launch_bounds__(256) void gemm1(const int* __restrict__ ctx,
                                             const bf16_t* __restrict__ EB,
                                             const bf16_t* __restrict__ Xg,
                                             const bf16_t* __restrict__ W,
                                             const float* __restrict__ b1,
                                             const float* __restrict__ w2,
                                             const float* __restrict__ b2,
                                             float* __restrict__ Fp) {
    __shared__ bf16_t As[2][128 * 64];        // 2 x 16 KB
    __shared__ bf16_t Bs[2][128 * 64];        // 2 x 16 KB
    __shared__ unsigned short ctxs[128 * 21]; // 5.375 KB (total 69.4 KB -> 2 blocks/CU)
    const int tid  = threadIdx.x;
    const int wave = tid >> 6, lane = tid & 63;
    const int s0 = blockIdx.x * 128, h0 = blockIdx.y * 128;
    const int wm = (wave >> 1) * 64;     // 2 wave-rows
    const int wn = (wave & 1) * 64;      // 2 wave-cols

    const int arow = tid >> 3;                         // 0..31
    const int akg  = (tid & 7) ^ (arow & 7);           // inverse-swizzled source k-group
    const bf16_t* gB = W + (size_t)(h0 + arow) * DP + akg * 8;

    const int lrow  = lane & 15;
    const int khalf = lane >> 4;         // 0..3
    const int lr7   = lrow & 7;

    // ctx table -> LDS (u16): rows s0..s0+127, flat copy
    for (int j = tid; j < 128 * C_CTX; j += 256)
        ctxs[j] = (unsigned short)ctx[s0 * C_CTX + j];
    asm volatile("s_waitcnt lgkmcnt(0)" ::: "memory");
    __builtin_amdgcn_s_barrier();

    // prologue: stage tile 0 (emb, c=0) into buf 0 — 8 loads
    {
        const int e0 = akg * 8;
#pragma unroll
        for (int i = 0; i < 4; ++i) {
            const int cv = ctxs[(i * 32 + arow) * 21];
            async_copy16(EB + (size_t)cv * 128 + e0, &As[0][(i * 256 + tid) * 8]);
        }
#pragma unroll
        for (int i = 0; i < 4; ++i)
            async_copy16(gB + (size_t)i * 32 * DP, &Bs[0][(i * 256 + tid) * 8]);
    }
    asm volatile("s_waitcnt vmcnt(0)" ::: "memory");
    __builtin_amdgcn_s_barrier();

    f32x4 acc[4][4] = {};
    const int NT = DP / 64;              // 54 (tiles 0..41 emb, 42..53 gz)
    for (int t = 0; t < NT; ++t) {
        const int cur = t & 1, nxt = cur ^ 1;
        const int tt = t + 1;
        const bool st = tt < NT;

        // all register fragments for this K-tile: 8 A + 8 B = 16 ds_read_b128
        bf16x8 a[2][2][2];     // [sp][ks][mt]
        bf16x8 b[2][2][2];     // [qn][ks][nt]
#pragma unroll
        for (int ks = 0; ks < 2; ++ks) {
            const int kgr = ((ks * 4 + khalf) ^ lr7) * 8;
#pragma unroll
            for (int sp = 0; sp < 2; ++sp)
#pragma unroll
                for (int mt = 0; mt < 2; ++mt)
                    a[sp][ks][mt] = *(const bf16x8*)&As[cur][(wm + sp * 32 + mt * 16 + lrow) * 64 + kgr];
#pragma unroll
            for (int qn = 0; qn < 2; ++qn)
#pragma unroll
                for (int nt = 0; nt < 2; ++nt)
                    b[qn][ks][nt] = *(const bf16x8*)&Bs[cur][(wn + qn * 32 + nt * 16 + lrow) * 64 + kgr];
        }
        // stage next tile into the other buffer (its readers finished at t-1)
        if (st) {
            if (tt < 42) {
                const int c_ = tt >> 1;
                const int e0 = (tt & 1) * 64 + akg * 8;
#pragma unroll
                for (int i = 0; i < 4; ++i) {
                    const int cv = ctxs[(i * 32 + arow) * 21 + c_];
                    async_copy16(EB + (size_t)cv * 128 + e0, &As[nxt][(i * 256 + tid) * 8]);
                }
            } else {
                const int m0 = (tt - 42) * 64 + akg * 8;
#pragma unroll
                for (int i = 0; i < 4; ++i)
                    async_copy16(Xg + (size_t)(s0 + i * 32 + arow) * GZP + m0, &As[nxt][(i * 256 + tid) * 8]);
            }
#pragma unroll
            for (int i = 0; i < 4; ++i)
                async_copy16(gB + (size_t)i * 32 * DP + tt * 64, &Bs[nxt][(i * 256 + tid) * 8]);
        }
        __builtin_amdgcn_s_setprio(1);
#pragma unroll
        for (int ks = 0; ks < 2; ++ks)
#pragma unroll
            for (int sp = 0; sp < 2; ++sp)
#pragma unroll
                for (int qn = 0; qn < 2; ++qn)
#pragma unroll
                    for (int mt = 0; mt < 2; ++mt)
#pragma unroll
                        for (int nt = 0; nt < 2; ++nt)
                            acc[sp * 2 + mt][qn * 2 + nt] = __builtin_amdgcn_mfma_f32_16x16x32_bf16(
                                a[sp][ks][mt], b[qn][ks][nt], acc[sp * 2 + mt][qn * 2 + nt], 0, 0, 0);
        __builtin_amdgcn_s_setprio(0);
        if (st) asm volatile("s_waitcnt vmcnt(0)" ::: "memory");
        __builtin_amdgcn_s_barrier();
    }

    // ---- fused feats epilogue ----
    bf16_t* Hl = &As[0][0];              // 128 x 128 bf16 (32 KB, spans As[0..1])
    bf16_t* Wl = &Bs[0][0];              // 32 x 128 bf16 (8 KB)

#pragma unroll
    for (int rep = 0; rep < 2; ++rep) {
        const int t8 = tid >> 3;            // 0..31 tag
        const int hl = (tid & 7) * 2 + rep; // 0..15 k-group
        const float* wsrc = w2 + (size_t)t8 * H_DIM + h0 + hl * 8;
        const float4 y0 = *(const float4*)wsrc;
        const float4 y1 = *(const float4*)(wsrc + 4);
        bf16x8 wv = {(bf16_t)y0.x, (bf16_t)y0.y, (bf16_t)y0.z, (bf16_t)y0.w,
                     (bf16_t)y1.x, (bf16_t)y1.y, (bf16_t)y1.z, (bf16_t)y1.w};
        *(bf16x8*)&Wl[(t8 * 16 + (hl ^ (t8 & 7))) * 8] = wv;
    }

    const int crow = (lane >> 4) * 4;
    const int ccol = lane & 15;
#pragma unroll
    for (int nt = 0; nt < 4; ++nt) {
        const int jl = wn + nt * 16 + ccol;          // 0..127 local h
        const float bv = b1[h0 + jl];
#pragma unroll
        for (int mt = 0; mt < 4; ++mt) {
#pragma unroll
            for (int r = 0; r < 4; ++r) {
                const int sl = wm + mt * 16 + crow + r;    // 0..127 local s
                const float v = acc[mt][nt][r] + bv;
                Hl[sl * 128 + ((jl >> 3) ^ (sl & 7)) * 8 + (jl & 7)] = (bf16_t)fmaxf(v, 0.f);
            }
        }
    }
    __syncthreads();

    f32x4 acc2[2][2] = {};
    const int wm2 = wave * 32;
#pragma unroll
    for (int ks = 0; ks < 4; ++ks) {
        const int slot = ((ks * 4 + khalf) ^ lr7) * 8;
        bf16x8 ah[2], bw[2];
#pragma unroll
        for (int mt = 0; mt < 2; ++mt)
            ah[mt] = *(const bf16x8*)&Hl[(wm2 + mt * 16 + lrow) * 128 + slot];
#pragma unroll
        for (int nt = 0; nt < 2; ++nt)
            bw[nt] = *(const bf16x8*)&Wl[(nt * 16 + lrow) * 128 + slot];
#pragma unroll
        for (int mt = 0; mt < 2; ++mt)
#pragma unroll
            for (int nt = 0; nt < 2; ++nt)
                acc2[mt][nt] = __builtin_amdgcn_mfma_f32_16x16x32_bf16(ah[mt], bw[nt], acc2[mt][nt], 0, 0, 0);
    }
    const int bj = h0 >> 7;
#pragma unroll
    for (int nt = 0; nt < 2; ++nt) {
        const int tcol = nt * 16 + ccol;
        const float badd = (bj == 7) ? b2[tcol] : 0.f;
#pragma unroll
        for (int mt = 0; mt < 2; ++mt) {
#pragma unroll
            for (int r = 0; r < 4; ++r) {
                const int sr = s0 + wm2 + mt * 16 + crow + r;
                Fp[((size_t)bj * S_LEN + sr) * T_TAG + tcol] = acc2[mt][nt][r] + badd;
            }
        }
    }
}

// ---------------- CRF pass A: per-chunk matrix-chain products + gold partial
// ONE chain per 64-lane wave; 2048 waves = 2 waves/SIMD. fl (the chunk's F
// rows, already in LDS for the chain) additionally feeds a per-chunk gold
// partial computed by the (blockIdx&3)==0 duplicate. Replaces the final
// fold's strided gold pass and the Fsum buffer entirely.
__global__ __launch_bounds__(512) void crfA(const float* __restrict__ Fp,
                                            const float* __restrict__ trans,
                                            float* __restrict__ QT,
                                            float* __restrict__ sigma,
                                            const int* __restrict__ lab,
                                            float* __restrict__ gold_part) {
    __shared__ float fl[L_CHUNK * 32];
    __shared__ float vb[8][64];
    __shared__ float wred[8];
    const int c    = blockIdx.x >> 2;
    const int tid  = threadIdx.x;
    const int wave = tid >> 6;
    const int lane = tid & 63;
    const int n    = lane & 31;
    const int h    = lane >> 5;                 // half: k in [h*16, h*16+16)
    const int p    = ((blockIdx.x & 3) << 3) + wave;
    const int s0   = c * L_CHUNK;
    for (int i = tid; i < L_CHUNK * 32; i += 512) {
        const size_t idx = (size_t)s0 * 32 + i;
        float accf = 0.f;
#pragma unroll
        for (int j = 0; j < 8; ++j) accf += Fp[(size_t)j * S_LEN * T_TAG + idx];
        fl[i] = accf;
    }
    __syncthreads();

    // gold partial (one duplicate block per chunk)
    const bool goldblk = (blockIdx.x & 3) == 0;
    float gterm = 0.f;
    if (goldblk && tid < L_CHUNK) {
        const int s  = s0 + tid;
        const int tg = lab[s];
        const int tp = (s == 0) ? START_TAG : lab[s - 1];
        gterm = fl[tid * 32 + tg] + trans[tg * T_TAG + tp];
    }
#pragma unroll
    for (int off = 32; off; off >>= 1) gterm += __shfl_down(gterm, off, 64);
    if (goldblk && lane == 0) wred[wave] = gterm;
    __syncthreads();
    if (goldblk && tid == 0) {
        float gsum = 0.f;
#pragma unroll
        for (int i = 0; i < 8; ++i) gsum += wred[i];   // waves 2..7 contributed 0
        gold_part[c] = gsum;
    }

    float etl[16];
#pragma unroll
    for (int j = 0; j < 16; ++j) etl[j] = __expf(trans[n * 32 + h * 16 + j]);

    float* vrow = &vb[wave][0];
    float v  = __expf(trans[n * 32 + p] + fl[n]);   // identical in both halves
    float sg = 0.f;
    for (int s = 1; s < L_CHUNK; ++s) {
        vrow[lane] = v;                             // vrow[k] = v[k] (dup at 32+k)
        __builtin_amdgcn_s_waitcnt(0xC07F);         // lgkmcnt(0): wave-coherent LDS
        float a0 = 0.f, a1 = 0.f, a2 = 0.f, a3 = 0.f;
#pragma unroll
        for (int q = 0; q < 4; ++q) {
            const float4 wv = *(const float4*)&vrow[h * 16 + q * 4];
            a0 = __builtin_fmaf(etl[q * 4 + 0], wv.x, a0);
            a1 = __builtin_fmaf(etl[q * 4 + 1], wv.y, a1);
            a2 = __builtin_fmaf(etl[q * 4 + 2], wv.z, a2);
            a3 = __builtin_fmaf(etl[q * 4 + 3], wv.w, a3);
        }
        float part = (a0 + a1) + (a2 + a3);
        part += __shfl_xor(part, 32);               // merge halves: full dot in all lanes
        v = __expf(fl[s * 32 + n]) * part;
        if ((s & 7) == 7) {
            float m = v;
#pragma unroll
            for (int off = 16; off; off >>= 1) m = fmaxf(m, __shfl_xor(m, off, 32));
            if (m > 0.f) { v *= 1.0f / m; sg += __logf(m); }
        }
    }
    if (h == 0) {
        QT[(c * 32 + p) * 32 + n] = v;
        if (n == 0) sigma[c * 32 + p] = sg;
    }
}

// ---------------- CRF pass B: parallel matrix fold ----------------
__global__ __launch_bounds__(1024) void crf_fold(const float* __restrict__ Qin,
                                                 const float* __restrict__ Sin,
                                                 const int fold, const int final,
                                                 float* __restrict__ Qout,
                                                 float* __restrict__ Sout,
                                                 const float* __restrict__ trans,
                                                 const float* __restrict__ gold_part,
                                                 const int* __restrict__ lab,
                                                 float* __restrict__ out) {
    __shared__ float A[32][33];
    __shared__ float M[32][33];
    __shared__ float sgf[32];
    __shared__ float gold_s;

    const int t = threadIdx.x;
    const int p = t >> 5, n = t & 31;
    const int c0 = blockIdx.x * fold;

    if (final && t == 0) {
        float s = 0.f;
#pragma unroll
        for (int i = 0; i < K_CHUNKS; ++i) s += gold_part[i];
        gold_s = s + trans[STOP_TAG * T_TAG + lab[S_LEN - 1]];
    }

    A[n][p] = Qin[(size_t)(c0 * 32 + p) * 32 + n];
    float sA = Sin[c0 * 32 + p];
    float mreg = Qin[(size_t)((c0 + 1) * 32 + p) * 32 + n];

    for (int i = 1; i < fold; ++i) {
        const float sMn = Sin[(c0 + i) * 32 + n];
        float mmax = sMn;
#pragma unroll
        for (int off = 16; off; off >>= 1) mmax = fmaxf(mmax, __shfl_xor(mmax, off, 32));
        const float sMp = Sin[(c0 + i) * 32 + p];
        __syncthreads();
        M[n][p] = mreg * __expf(sMp - mmax);
        if (i + 1 < fold) mreg = Qin[(size_t)((c0 + i + 1) * 32 + p) * 32 + n];
        __syncthreads();
        float acc = 0.f;
#pragma unroll 8
        for (int k = 0; k < 32; ++k)
            acc += M[n][k] * A[k][p];
        float cm = acc;
#pragma unroll
        for (int off = 16; off; off >>= 1) cm = fmaxf(cm, __shfl_xor(cm, off, 32));
        cm = fmaxf(cm, 1e-37f);
        __syncthreads();
        A[n][p] = acc / cm;
        sA = sA + mmax + __logf(cm);
    }
    __syncthreads();

    if (!final) {
        Qout[(size_t)(blockIdx.x * 32 + p) * 32 + n] = A[n][p];
        if (n == 0) Sout[blockIdx.x * 32 + p] = sA;
        return;
    }

    if (n == 0) sgf[p] = sA;
    __syncthreads();
    if (t < 32) {
        float v = A[t][START_TAG] * __expf(trans[STOP_TAG * T_TAG + t]);
#pragma unroll
        for (int off = 16; off; off >>= 1) v += __shfl_xor(v, off, 32);
        if (t == 0) out[0] = sgf[START_TAG] + __logf(v) - gold_s;
    }
}

// ---------------- launch ----------------
extern "C" void kernel_launch(void* const* d_in, const int* in_sizes, int n_in,
                              void* d_out, int out_size, void* d_ws, size_t ws_size,
                              hipStream_t stream) {
    const int*   ctx   = (const int*)d_in[0];
    const float* gz    = (const float*)d_in[1];
    const int*   lab   = (const int*)d_in[2];
    const float* emb   = (const float*)d_in[3];
    const float* w1    = (const float*)d_in[4];
    const float* b1    = (const float*)d_in[5];
    const float* w2    = (const float*)d_in[6];
    const float* b2    = (const float*)d_in[7];
    const float* trans = (const float*)d_in[8];
    float* out = (float*)d_out;

    char* ws = (char*)d_ws;
    bf16_t* W1b = (bf16_t*)(ws + 0);               // 1024*3456*2 =  7,077,888
    bf16_t* EB  = (bf16_t*)(ws + 7077888);         // 8000*128*2  =  2,048,000
    bf16_t* Xg  = (bf16_t*)(ws + 9126400);         // 8192*768*2  = 12,582,912
    float*  Fp  = (float*)(ws + 21709312);         // 8*8192*32*4 =  8,388,608
    float*  goldp = (float*)(ws + 30097920);       // 64*4        =        256
    float*  QT  = (float*)(ws + 31146496);         // 64*32*32*4  =    262,144
    float*  sg  = (float*)(ws + 31408640);         // 64*32*4     =      8,192
    float*  Q1  = (float*)(ws + 31416832);         // 8*32*32*4   =     32,768
    float*  S1  = (float*)(ws + 31449600);         // 8*32*4      =      1,024

    build_all<<<3572, 256, 0, stream>>>(ctx, gz, emb, w1, Xg, W1b, EB);
    gemm1<<<dim3(S_LEN / 128, H_DIM / 128), 256, 0, stream>>>(ctx, EB, Xg, W1b, b1, w2, b2, Fp);
    crfA<<<K_CHUNKS * 4, 512, 0, stream>>>(Fp, trans, QT, sg, lab, goldp);
    crf_fold<<<8, 1024, 0, stream>>>(QT, sg, 8, 0, Q1, S1, trans, nullptr, nullptr, nullptr);
    crf_fold<<<1, 1024, 0, stream>>>(Q1, S1, 8, 1, nullptr, nullptr, trans, goldp, lab, out);
}